// Round 3
// baseline (2466.110 us; speedup 1.0000x reference)
//
#include <hip/hip_runtime.h>
#include <hip/hip_bf16.h>

#define BB 16
#define NN 1024
#define KNN 20

// ---------------- fallback: encode ws_size into output if workspace too small ----------------
__global__ void fallback_k(float* __restrict__ out, int n, float c){
    int i = blockIdx.x*256 + threadIdx.x;
    if(i < n) out[i] = c;
}

// ---------------- squared norms (sequential fma order — must match knn_k dot order) ----------------
template<int D>
__global__ void sqnorm_k(const float* __restrict__ h, int S, float* __restrict__ sqn){
    int i = blockIdx.x*256 + threadIdx.x;
    if(i < BB*NN){
        const float* r = h + (size_t)i*S;
        float s = 0.f;
        for(int d=0; d<D; d++){ float v = r[d]; s = fmaf(v, v, s); }
        sqn[i] = s;
    }
}

// ---------------- fused pairwise-dist + top-20 (no global dist tensor) ----------------
// one block = one batch b, 4 query rows. Phase 1: tile-GEMM 4x1024 dist stripe into LDS.
// Phase 2: 4 waves, one row each, register+shuffle top-20.
// Diagonal exactly 0: dot fma chain order d=0..D-1 matches sqnorm_k.
template<int D>
__global__ __launch_bounds__(256) void knn_k(const float* __restrict__ h, int S,
                                             const float* __restrict__ sqn,
                                             int* __restrict__ idx){
    constexpr int SB = (D % 4 == 0) ? (D + 4) : 8;   // 16B-aligned row stride
    const int b   = blockIdx.y;
    const int n0  = blockIdx.x * 4;
    const int tid = threadIdx.x;
    const int lane = tid & 63;
    const int wv   = tid >> 6;

    __shared__ float rowsA[4*SB];
    __shared__ float Bs[64*SB];
    __shared__ float4 distb4[4*256];
    __shared__ float sqnA[4];
    __shared__ float sqnB[64];
    float* distb = (float*)distb4;

    const float* hb = h + (size_t)b*NN*S;
    for(int l=tid; l<4*D; l+=256){
        int r = l / D, d = l % D;
        rowsA[r*SB + d] = hb[(size_t)(n0+r)*S + d];
    }
    if(tid < 4) sqnA[tid] = sqn[b*NN + n0 + tid];

    const int r0 = wv;            // row this thread computes in phase 1
    const int ml = lane;
    for(int mc=0; mc<16; mc++){
        __syncthreads();          // protect Bs/sqnB from previous iteration's readers
        int m0 = mc*64;
        for(int l=tid; l<64*D; l+=256){
            int r = l / D, d = l % D;
            Bs[r*SB + d] = hb[(size_t)(m0+r)*S + d];
        }
        if(tid < 64) sqnB[tid] = sqn[b*NN + m0 + tid];
        __syncthreads();
        float acc = 0.f;
        if constexpr (D % 4 == 0){
            for(int d4=0; d4<D; d4+=4){
                float4 bv = *(const float4*)&Bs[ml*SB + d4];
                float4 a0 = *(const float4*)&rowsA[r0*SB + d4];
                acc = fmaf(a0.x, bv.x, acc); acc = fmaf(a0.y, bv.y, acc);
                acc = fmaf(a0.z, bv.z, acc); acc = fmaf(a0.w, bv.w, acc);
            }
        } else {
            for(int d=0; d<D; d++){
                acc = fmaf(rowsA[r0*SB + d], Bs[ml*SB + d], acc);
            }
        }
        distb[r0*1024 + m0 + ml] = sqnA[r0] + sqnB[ml] - 2.f*acc;
    }
    __syncthreads();

    // top-20 per row; ties -> lowest index (matches lax.top_k stability)
    {
        const int rr = wv;
        float v[16];
        const float4* d4p = (const float4*)(distb + rr*1024);
        #pragma unroll
        for(int q=0;q<4;q++){
            float4 f = d4p[lane + 64*q];
            v[4*q+0]=f.x; v[4*q+1]=f.y; v[4*q+2]=f.z; v[4*q+3]=f.w;
        }
        int* out = idx + ((size_t)b*NN + n0 + rr)*KNN;
        const float FMAXV = 3.402823466e38f;
        for(int t=0;t<KNN;t++){
            float bvv = FMAXV; int bi = 0x7fffffff;
            #pragma unroll
            for(int q=0;q<16;q++){
                if(v[q] < bvv){ bvv = v[q]; bi = 4*(lane + 64*(q>>2)) + (q&3); }
            }
            #pragma unroll
            for(int off=32; off>0; off>>=1){
                float ov = __shfl_xor(bvv, off);
                int   oi = __shfl_xor(bi, off);
                if(ov < bvv || (ov == bvv && oi < bi)){ bvv = ov; bi = oi; }
            }
            if(lane == 0) out[t] = bi;
            int ol = (bi >> 2) & 63;
            if(lane == ol){
                int q = ((bi >> 8) << 2) | (bi & 3);
                v[q] = FMAXV;
            }
        }
    }
}

// ---------------- tiled GEMM: T[16384, O] = h[16384, D(stride S)] @ theta[O, D]^T ----------------
template<int D, int O>
__global__ __launch_bounds__(256) void featT_k(const float* __restrict__ h, int S,
                                               const float* __restrict__ th,
                                               float* __restrict__ T){
    int ot = blockIdx.x, nt = blockIdx.y;
    int tid = threadIdx.x, tx = tid & 15, ty = tid >> 4;
    __shared__ float As[64][33];
    __shared__ float Ws[64][33];
    float acc[4][4] = {};
    for(int kk=0; kk<D; kk+=32){
        for(int l=tid; l<64*32; l+=256){
            int r = l>>5, c = l&31, d = kk + c;
            As[r][c] = (d < D) ? h[(size_t)(nt*64+r)*S + d] : 0.f;
            Ws[r][c] = (d < D) ? th[(size_t)(ot*64+r)*D + d] : 0.f;
        }
        __syncthreads();
        #pragma unroll
        for(int k=0;k<32;k++){
            float a[4], bv[4];
            #pragma unroll
            for(int i=0;i<4;i++) a[i]  = As[ty+16*i][k];
            #pragma unroll
            for(int j=0;j<4;j++) bv[j] = Ws[tx+16*j][k];
            #pragma unroll
            for(int i=0;i<4;i++)
                #pragma unroll
                for(int j=0;j<4;j++) acc[i][j] = fmaf(a[i], bv[j], acc[i][j]);
        }
        __syncthreads();
    }
    #pragma unroll
    for(int i=0;i<4;i++){
        int rw = nt*64 + ty + 16*i;
        #pragma unroll
        for(int j=0;j<4;j++){
            int o = ot*64 + tx + 16*j;
            T[(size_t)rw*O + o] = acc[i][j];
        }
    }
}

// ---------------- gather 20 neighbors of T, max, + (phi-theta)(x_i) inline, leaky ----------------
template<int D, int O>
__global__ void gather_k(const float* __restrict__ T, const float* __restrict__ h, int S,
                         const float* __restrict__ th, const float* __restrict__ ph,
                         const int* __restrict__ idx, float* __restrict__ outp){
    int bn = blockIdx.x, b = bn >> 10;
    int tid = threadIdx.x;
    __shared__ int nb[KNN];
    __shared__ float hr[D];
    if(tid < KNN) nb[tid] = idx[bn*KNN + tid] & (NN-1);   // mask: no fault even if idx bad
    for(int d=tid; d<D; d+=O) hr[d] = h[(size_t)bn*S + d];
    __syncthreads();
    const float* Tb = T + (size_t)b*NN*O;
    int o = tid;                              // blockDim.x == O
    float m = -3.402823466e38f;
    #pragma unroll
    for(int k=0;k<KNN;k++) m = fmaxf(m, Tb[(size_t)nb[k]*O + o]);
    float p = 0.f, t = 0.f;
    for(int d=0; d<D; d++){
        t = fmaf(hr[d], th[(size_t)o*D+d], t);
        p = fmaf(hr[d], ph[(size_t)o*D+d], p);
    }
    float v = m + (p - t);
    v = (v > 0.f) ? v : 0.2f*v;
    outp[(size_t)bn*512 + o] = v;
}

// ---------------- projection GEMM (16K x 512 x 1024) with fused partial max/sum pool ----------------
__global__ __launch_bounds__(256) void proj_k(const float* __restrict__ hs, const float* __restrict__ w,
                                              float* __restrict__ pmax, float* __restrict__ psum){
    int ot = blockIdx.x, nt = blockIdx.y, b = blockIdx.z;
    int tid = threadIdx.x;
    int tx = tid & 15, ty = tid >> 4;
    __shared__ float As[64][33];
    __shared__ float Ws[64][33];
    __shared__ float red[16][64];
    float acc[4][4] = {};
    const float* hb = hs + (size_t)b*NN*512;
    for(int kk=0; kk<512; kk+=32){
        for(int l=tid; l<64*32; l+=256){
            int r = l>>5, c = l&31;
            As[r][c] = hb[(size_t)(nt*64+r)*512 + kk + c];
            Ws[r][c] = w[(size_t)(ot*64+r)*512 + kk + c];
        }
        __syncthreads();
        #pragma unroll
        for(int k=0;k<32;k++){
            float a[4], bv[4];
            #pragma unroll
            for(int i=0;i<4;i++) a[i]  = As[ty+16*i][k];
            #pragma unroll
            for(int j=0;j<4;j++) bv[j] = Ws[tx+16*j][k];
            #pragma unroll
            for(int i=0;i<4;i++)
                #pragma unroll
                for(int j=0;j<4;j++) acc[i][j] = fmaf(a[i], bv[j], acc[i][j]);
        }
        __syncthreads();
    }
    float tmax[4], tsum[4];
    #pragma unroll
    for(int j=0;j<4;j++){
        tmax[j] = acc[0][j]; tsum[j] = acc[0][j];
        #pragma unroll
        for(int i=1;i<4;i++){ tmax[j] = fmaxf(tmax[j], acc[i][j]); tsum[j] += acc[i][j]; }
    }
    #pragma unroll
    for(int j=0;j<4;j++) red[ty][tx+16*j] = tmax[j];
    __syncthreads();
    if(tid < 64){
        float m = red[0][tid];
        for(int r=1;r<16;r++) m = fmaxf(m, red[r][tid]);
        pmax[((size_t)b*16 + nt)*1024 + ot*64 + tid] = m;
    }
    __syncthreads();
    #pragma unroll
    for(int j=0;j<4;j++) red[ty][tx+16*j] = tsum[j];
    __syncthreads();
    if(tid < 64){
        float s = 0.f;
        for(int r=0;r<16;r++) s += red[r][tid];
        psum[((size_t)b*16 + nt)*1024 + ot*64 + tid] = s;
    }
}

// ---------------- combine n-tiles, add bias -> pooled [16, 2048] (max | mean) ----------------
__global__ void pool_final_k(const float* __restrict__ pmax, const float* __restrict__ psum,
                             const float* __restrict__ pb, float* __restrict__ pooled){
    int i = blockIdx.x*256 + threadIdx.x;   // b*1024 + o
    if(i >= BB*1024) return;
    int b = i >> 10, o = i & 1023;
    float m = -3.402823466e38f, s = 0.f;
    for(int t=0;t<16;t++){
        m = fmaxf(m, pmax[((size_t)b*16 + t)*1024 + o]);
        s += psum[((size_t)b*16 + t)*1024 + o];
    }
    float bias = pb[o];
    pooled[b*2048 + o]        = m + bias;
    pooled[b*2048 + 1024 + o] = s * (1.f/1024.f) + bias;
}

// ---------------- head FC + BatchNorm(batch of 16) + leaky; one block per feature ----------------
template<int IN>
__global__ __launch_bounds__(256) void head_bn_k(const float* __restrict__ in, const float* __restrict__ w,
                                                 const float* __restrict__ bias, const float* __restrict__ g,
                                                 const float* __restrict__ bt, float* __restrict__ out, int OUT){
    int o = blockIdx.x;
    int tid = threadIdx.x, bb = tid >> 4, s = tid & 15;
    const float* ir = in + (size_t)bb*IN;
    const float* wr = w  + (size_t)o*IN;
    float acc = 0.f;
    for(int d=s; d<IN; d+=16) acc = fmaf(ir[d], wr[d], acc);
    #pragma unroll
    for(int off=8; off>0; off>>=1) acc += __shfl_xor(acc, off);
    __shared__ float vals[16];
    __shared__ float stats[2];
    if(s == 0) vals[bb] = acc + bias[o];
    __syncthreads();
    if(tid == 0){
        float mu = 0.f;
        for(int q=0;q<16;q++) mu += vals[q];
        mu *= (1.f/16.f);
        float var = 0.f;
        for(int q=0;q<16;q++){ float d = vals[q]-mu; var = fmaf(d,d,var); }
        var *= (1.f/16.f);
        stats[0] = mu; stats[1] = rsqrtf(var + 1e-5f);
    }
    __syncthreads();
    if(s == 0){
        float v = (vals[bb]-stats[0])*stats[1]*g[o] + bt[o];
        v = (v > 0.f) ? v : 0.2f*v;
        out[(size_t)bb*OUT + o] = v;
    }
}

// ---------------- final linear -> f32 out [16,40] ----------------
__global__ __launch_bounds__(256) void head_out_k(const float* __restrict__ in, const float* __restrict__ w,
                                                  const float* __restrict__ bias, float* __restrict__ out){
    int o = blockIdx.x;   // 40
    int tid = threadIdx.x, bb = tid >> 4, s = tid & 15;
    const float* ir = in + (size_t)bb*256;
    float acc = 0.f;
    for(int d=s; d<256; d+=16) acc = fmaf(ir[d], w[o*256+d], acc);
    #pragma unroll
    for(int off=8; off>0; off>>=1) acc += __shfl_xor(acc, off);
    if(s == 0) out[bb*40 + o] = acc + bias[o];
}

extern "C" void kernel_launch(void* const* d_in, const int* in_sizes, int n_in,
                              void* d_out, int out_size, void* d_ws, size_t ws_size,
                              hipStream_t stream) {
    const float* x       = (const float*)d_in[0];
    const float* th[4]   = {(const float*)d_in[1], (const float*)d_in[3], (const float*)d_in[5], (const float*)d_in[7]};
    const float* ph[4]   = {(const float*)d_in[2], (const float*)d_in[4], (const float*)d_in[6], (const float*)d_in[8]};
    const float* proj_w  = (const float*)d_in[9];
    const float* proj_b  = (const float*)d_in[10];
    const float* emb0_w  = (const float*)d_in[11];
    const float* emb0_b  = (const float*)d_in[12];
    const float* bn0_g   = (const float*)d_in[13];
    const float* bn0_b   = (const float*)d_in[14];
    const float* emb1_w  = (const float*)d_in[15];
    const float* emb1_b  = (const float*)d_in[16];
    const float* bn1_g   = (const float*)d_in[17];
    const float* bn1_b   = (const float*)d_in[18];
    const float* out_w   = (const float*)d_in[19];
    const float* out_b   = (const float*)d_in[20];
    float* outp = (float*)d_out;

    // workspace layout (float elements)
    const size_t OFF_HS  = 0;                       // 16384 x 512        = 8,388,608
    const size_t OFF_T   = 8388608;                 // 16384 x 256 max    = 4,194,304
    const size_t OFF_SQN = 12582912;                // 16384
    const size_t OFF_IDX = 12599296;                // 16384 x 20 ints    =   327,680
    const size_t REQ_FL  = 12926976;
    const size_t REQ     = REQ_FL * 4;              // 51,707,904 bytes

    if(ws_size < REQ){
        // diagnostic fallback: absmax will encode ws_size in MB-ish units
        fallback_k<<<(out_size+255)/256, 256, 0, stream>>>(outp, out_size, (float)((double)ws_size*1e-6));
        return;
    }

    float* Wf   = (float*)d_ws;
    float* hs   = Wf + OFF_HS;
    float* T    = Wf + OFF_T;
    float* sqn  = Wf + OFF_SQN;
    int*   idxb = (int*)(Wf + OFF_IDX);
    // post-layer aliases inside T region (T dead after last gather)
    float* pmax   = T;
    float* psum   = T + 262144;
    float* pooled = T + 524288;
    float* z0     = T + 557056;
    float* z1     = T + 565248;

    // ---- layer 0: h=x (S=3,D=3) -> O=64 at hs ch 0
    sqnorm_k<3><<<64,256,0,stream>>>(x, 3, sqn);
    knn_k<3><<<dim3(256,16),256,0,stream>>>(x, 3, sqn, idxb);
    featT_k<3,64><<<dim3(1,256),256,0,stream>>>(x, 3, th[0], T);
    gather_k<3,64><<<BB*NN,64,0,stream>>>(T, x, 3, th[0], ph[0], idxb, hs + 0);

    // ---- layer 1: h=hs[:,0:64] (S=512,D=64) -> O=64 at ch 64
    sqnorm_k<64><<<64,256,0,stream>>>(hs + 0, 512, sqn);
    knn_k<64><<<dim3(256,16),256,0,stream>>>(hs + 0, 512, sqn, idxb);
    featT_k<64,64><<<dim3(1,256),256,0,stream>>>(hs + 0, 512, th[1], T);
    gather_k<64,64><<<BB*NN,64,0,stream>>>(T, hs + 0, 512, th[1], ph[1], idxb, hs + 64);

    // ---- layer 2: h=hs[:,64:128] (D=64) -> O=128 at ch 128
    sqnorm_k<64><<<64,256,0,stream>>>(hs + 64, 512, sqn);
    knn_k<64><<<dim3(256,16),256,0,stream>>>(hs + 64, 512, sqn, idxb);
    featT_k<64,128><<<dim3(2,256),256,0,stream>>>(hs + 64, 512, th[2], T);
    gather_k<64,128><<<BB*NN,128,0,stream>>>(T, hs + 64, 512, th[2], ph[2], idxb, hs + 128);

    // ---- layer 3: h=hs[:,128:256] (D=128) -> O=256 at ch 256
    sqnorm_k<128><<<64,256,0,stream>>>(hs + 128, 512, sqn);
    knn_k<128><<<dim3(256,16),256,0,stream>>>(hs + 128, 512, sqn, idxb);
    featT_k<128,256><<<dim3(4,256),256,0,stream>>>(hs + 128, 512, th[3], T);
    gather_k<128,256><<<BB*NN,256,0,stream>>>(T, hs + 128, 512, th[3], ph[3], idxb, hs + 256);

    // ---- projection + pooling
    proj_k<<<dim3(16,16,16),256,0,stream>>>(hs, proj_w, pmax, psum);
    pool_final_k<<<64,256,0,stream>>>(pmax, psum, proj_b, pooled);

    // ---- head
    head_bn_k<2048><<<512,256,0,stream>>>(pooled, emb0_w, emb0_b, bn0_g, bn0_b, z0, 512);
    head_bn_k<512><<<256,256,0,stream>>>(z0, emb1_w, emb1_b, bn1_g, bn1_b, z1, 256);
    head_out_k<<<40,256,0,stream>>>(z1, out_w, out_b, outp);
}

// Round 4
// 1801.579 us; speedup vs baseline: 1.3689x; 1.3689x over previous
//
#include <hip/hip_runtime.h>
#include <hip/hip_bf16.h>

#define BB 16
#define NN 1024
#define KNN 20

// ---------------- fallback: encode ws_size into output if workspace too small ----------------
__global__ void fallback_k(float* __restrict__ out, int n, float c){
    int i = blockIdx.x*256 + threadIdx.x;
    if(i < n) out[i] = c;
}

// ---------------- squared norms (sequential fma order — must match knn_k dot order) ----------------
template<int D>
__global__ void sqnorm_k(const float* __restrict__ h, int S, float* __restrict__ sqn){
    int i = blockIdx.x*256 + threadIdx.x;
    if(i < BB*NN){
        const float* r = h + (size_t)i*S;
        float s = 0.f;
        for(int d=0; d<D; d++){ float v = r[d]; s = fmaf(v, v, s); }
        sqn[i] = s;
    }
}

// ---------------- fused pairwise-dist + top-20 (no global dist tensor) ----------------
template<int D>
__global__ __launch_bounds__(256) void knn_k(const float* __restrict__ h, int S,
                                             const float* __restrict__ sqn,
                                             int* __restrict__ idx){
    constexpr int SB = (D % 4 == 0) ? (D + 4) : 8;   // 16B-aligned row stride
    const int b   = blockIdx.y;
    const int n0  = blockIdx.x * 4;
    const int tid = threadIdx.x;
    const int lane = tid & 63;
    const int wv   = tid >> 6;

    __shared__ float rowsA[4*SB];
    __shared__ float Bs[64*SB];
    __shared__ float4 distb4[4*256];
    __shared__ float sqnA[4];
    __shared__ float sqnB[64];
    float* distb = (float*)distb4;

    const float* hb = h + (size_t)b*NN*S;
    for(int l=tid; l<4*D; l+=256){
        int r = l / D, d = l % D;
        rowsA[r*SB + d] = hb[(size_t)(n0+r)*S + d];
    }
    if(tid < 4) sqnA[tid] = sqn[b*NN + n0 + tid];

    const int r0 = wv;
    const int ml = lane;
    for(int mc=0; mc<16; mc++){
        __syncthreads();
        int m0 = mc*64;
        for(int l=tid; l<64*D; l+=256){
            int r = l / D, d = l % D;
            Bs[r*SB + d] = hb[(size_t)(m0+r)*S + d];
        }
        if(tid < 64) sqnB[tid] = sqn[b*NN + m0 + tid];
        __syncthreads();
        float acc = 0.f;
        if constexpr (D % 4 == 0){
            for(int d4=0; d4<D; d4+=4){
                float4 bv = *(const float4*)&Bs[ml*SB + d4];
                float4 a0 = *(const float4*)&rowsA[r0*SB + d4];
                acc = fmaf(a0.x, bv.x, acc); acc = fmaf(a0.y, bv.y, acc);
                acc = fmaf(a0.z, bv.z, acc); acc = fmaf(a0.w, bv.w, acc);
            }
        } else {
            for(int d=0; d<D; d++){
                acc = fmaf(rowsA[r0*SB + d], Bs[ml*SB + d], acc);
            }
        }
        distb[r0*1024 + m0 + ml] = sqnA[r0] + sqnB[ml] - 2.f*acc;
    }
    __syncthreads();

    // top-20 per row; ties -> lowest index (matches lax.top_k stability)
    {
        const int rr = wv;
        float v[16];
        const float4* d4p = (const float4*)(distb + rr*1024);
        #pragma unroll
        for(int q=0;q<4;q++){
            float4 f = d4p[lane + 64*q];
            v[4*q+0]=f.x; v[4*q+1]=f.y; v[4*q+2]=f.z; v[4*q+3]=f.w;
        }
        int* out = idx + ((size_t)b*NN + n0 + rr)*KNN;
        const float FMAXV = 3.402823466e38f;
        for(int t=0;t<KNN;t++){
            float bvv = FMAXV; int bi = 0x7fffffff;
            #pragma unroll
            for(int q=0;q<16;q++){
                if(v[q] < bvv){ bvv = v[q]; bi = 4*(lane + 64*(q>>2)) + (q&3); }
            }
            #pragma unroll
            for(int off=32; off>0; off>>=1){
                float ov = __shfl_xor(bvv, off);
                int   oi = __shfl_xor(bi, off);
                if(ov < bvv || (ov == bvv && oi < bi)){ bvv = ov; bi = oi; }
            }
            if(lane == 0) out[t] = bi;
            int ol = (bi >> 2) & 63;
            if(lane == ol){
                int q = ((bi >> 8) << 2) | (bi & 3);
                v[q] = FMAXV;
            }
        }
    }
}

// ---------------- tiled dual GEMM: T = h@theta^T ; U = h@(phi-theta)^T ----------------
template<int D, int O>
__global__ __launch_bounds__(256) void featTU_k(const float* __restrict__ h, int S,
                                                const float* __restrict__ th,
                                                const float* __restrict__ ph,
                                                float* __restrict__ T, float* __restrict__ U){
    int ot = blockIdx.x, nt = blockIdx.y;
    int tid = threadIdx.x, tx = tid & 15, ty = tid >> 4;
    __shared__ float As[64][33];
    __shared__ float Wt[64][33];
    __shared__ float Wp[64][33];
    float acct[4][4] = {};
    float accp[4][4] = {};
    for(int kk=0; kk<D; kk+=32){
        for(int l=tid; l<64*32; l+=256){
            int r = l>>5, c = l&31, d = kk + c;
            As[r][c] = (d < D) ? h[(size_t)(nt*64+r)*S + d] : 0.f;
            Wt[r][c] = (d < D) ? th[(size_t)(ot*64+r)*D + d] : 0.f;
            Wp[r][c] = (d < D) ? ph[(size_t)(ot*64+r)*D + d] : 0.f;
        }
        __syncthreads();
        #pragma unroll
        for(int k=0;k<32;k++){
            float a[4], bt[4], bp[4];
            #pragma unroll
            for(int i=0;i<4;i++) a[i]  = As[ty+16*i][k];
            #pragma unroll
            for(int j=0;j<4;j++){ bt[j] = Wt[tx+16*j][k]; bp[j] = Wp[tx+16*j][k]; }
            #pragma unroll
            for(int i=0;i<4;i++)
                #pragma unroll
                for(int j=0;j<4;j++){
                    acct[i][j] = fmaf(a[i], bt[j], acct[i][j]);
                    accp[i][j] = fmaf(a[i], bp[j], accp[i][j]);
                }
        }
        __syncthreads();
    }
    #pragma unroll
    for(int i=0;i<4;i++){
        int rw = nt*64 + ty + 16*i;
        #pragma unroll
        for(int j=0;j<4;j++){
            int o = ot*64 + tx + 16*j;
            T[(size_t)rw*O + o] = acct[i][j];
            U[(size_t)rw*O + o] = accp[i][j] - acct[i][j];
        }
    }
}

// ---------------- gather 20 neighbors of T, max, + U, leaky ----------------
template<int O>
__global__ __launch_bounds__(256) void gather2_k(const float* __restrict__ T, const float* __restrict__ U,
                                                 const int* __restrict__ idx, float* __restrict__ outp){
    constexpr int P = 256 / O;           // points per block
    int bn0 = blockIdx.x * P;
    int tid = threadIdx.x;
    int p = tid / O, o = tid % O;
    int bn = bn0 + p;
    int b  = bn >> 10;
    __shared__ int nb[P*KNN];
    if(tid < P*KNN){
        int pp = tid / KNN, k = tid % KNN;
        nb[pp*KNN + k] = idx[(size_t)(bn0+pp)*KNN + k] & (NN-1);  // mask: never faults
    }
    __syncthreads();
    const float* Tb = T + (size_t)b*NN*O;
    float m = -3.402823466e38f;
    #pragma unroll
    for(int k=0;k<KNN;k++) m = fmaxf(m, Tb[(size_t)nb[p*KNN+k]*O + o]);
    float v = m + U[(size_t)bn*O + o];
    v = (v > 0.f) ? v : 0.2f*v;
    outp[(size_t)bn*512 + o] = v;
}

// ---------------- projection GEMM (16K x 512 x 1024) with fused partial max/sum pool ----------------
__global__ __launch_bounds__(256) void proj_k(const float* __restrict__ hs, const float* __restrict__ w,
                                              float* __restrict__ pmax, float* __restrict__ psum){
    int ot = blockIdx.x, nt = blockIdx.y, b = blockIdx.z;
    int tid = threadIdx.x;
    int tx = tid & 15, ty = tid >> 4;
    __shared__ float As[64][33];
    __shared__ float Ws[64][33];
    __shared__ float red[16][64];
    float acc[4][4] = {};
    const float* hb = hs + (size_t)b*NN*512;
    for(int kk=0; kk<512; kk+=32){
        for(int l=tid; l<64*32; l+=256){
            int r = l>>5, c = l&31;
            As[r][c] = hb[(size_t)(nt*64+r)*512 + kk + c];
            Ws[r][c] = w[(size_t)(ot*64+r)*512 + kk + c];
        }
        __syncthreads();
        #pragma unroll
        for(int k=0;k<32;k++){
            float a[4], bv[4];
            #pragma unroll
            for(int i=0;i<4;i++) a[i]  = As[ty+16*i][k];
            #pragma unroll
            for(int j=0;j<4;j++) bv[j] = Ws[tx+16*j][k];
            #pragma unroll
            for(int i=0;i<4;i++)
                #pragma unroll
                for(int j=0;j<4;j++) acc[i][j] = fmaf(a[i], bv[j], acc[i][j]);
        }
        __syncthreads();
    }
    float tmax[4], tsum[4];
    #pragma unroll
    for(int j=0;j<4;j++){
        tmax[j] = acc[0][j]; tsum[j] = acc[0][j];
        #pragma unroll
        for(int i=1;i<4;i++){ tmax[j] = fmaxf(tmax[j], acc[i][j]); tsum[j] += acc[i][j]; }
    }
    #pragma unroll
    for(int j=0;j<4;j++) red[ty][tx+16*j] = tmax[j];
    __syncthreads();
    if(tid < 64){
        float m = red[0][tid];
        for(int r=1;r<16;r++) m = fmaxf(m, red[r][tid]);
        pmax[((size_t)b*16 + nt)*1024 + ot*64 + tid] = m;
    }
    __syncthreads();
    #pragma unroll
    for(int j=0;j<4;j++) red[ty][tx+16*j] = tsum[j];
    __syncthreads();
    if(tid < 64){
        float s = 0.f;
        for(int r=0;r<16;r++) s += red[r][tid];
        psum[((size_t)b*16 + nt)*1024 + ot*64 + tid] = s;
    }
}

// ---------------- combine n-tiles, add bias -> pooled [16, 2048] (max | mean) ----------------
__global__ void pool_final_k(const float* __restrict__ pmax, const float* __restrict__ psum,
                             const float* __restrict__ pb, float* __restrict__ pooled){
    int i = blockIdx.x*256 + threadIdx.x;   // b*1024 + o
    if(i >= BB*1024) return;
    int b = i >> 10, o = i & 1023;
    float m = -3.402823466e38f, s = 0.f;
    for(int t=0;t<16;t++){
        m = fmaxf(m, pmax[((size_t)b*16 + t)*1024 + o]);
        s += psum[((size_t)b*16 + t)*1024 + o];
    }
    float bias = pb[o];
    pooled[b*2048 + o]        = m + bias;
    pooled[b*2048 + 1024 + o] = s * (1.f/1024.f) + bias;
}

// ---------------- head FC + BatchNorm(batch of 16) + leaky; one block per feature ----------------
template<int IN>
__global__ __launch_bounds__(256) void head_bn_k(const float* __restrict__ in, const float* __restrict__ w,
                                                 const float* __restrict__ bias, const float* __restrict__ g,
                                                 const float* __restrict__ bt, float* __restrict__ out, int OUT){
    int o = blockIdx.x;
    int tid = threadIdx.x, bb = tid >> 4, s = tid & 15;
    const float* ir = in + (size_t)bb*IN;
    const float* wr = w  + (size_t)o*IN;
    float acc = 0.f;
    for(int d=s; d<IN; d+=16) acc = fmaf(ir[d], wr[d], acc);
    #pragma unroll
    for(int off=8; off>0; off>>=1) acc += __shfl_xor(acc, off);
    __shared__ float vals[16];
    __shared__ float stats[2];
    if(s == 0) vals[bb] = acc + bias[o];
    __syncthreads();
    if(tid == 0){
        float mu = 0.f;
        for(int q=0;q<16;q++) mu += vals[q];
        mu *= (1.f/16.f);
        float var = 0.f;
        for(int q=0;q<16;q++){ float d = vals[q]-mu; var = fmaf(d,d,var); }
        var *= (1.f/16.f);
        stats[0] = mu; stats[1] = rsqrtf(var + 1e-5f);
    }
    __syncthreads();
    if(s == 0){
        float v = (vals[bb]-stats[0])*stats[1]*g[o] + bt[o];
        v = (v > 0.f) ? v : 0.2f*v;
        out[(size_t)bb*OUT + o] = v;
    }
}

// ---------------- final linear -> f32 out [16,40] ----------------
__global__ __launch_bounds__(256) void head_out_k(const float* __restrict__ in, const float* __restrict__ w,
                                                  const float* __restrict__ bias, float* __restrict__ out){
    int o = blockIdx.x;   // 40
    int tid = threadIdx.x, bb = tid >> 4, s = tid & 15;
    const float* ir = in + (size_t)bb*256;
    float acc = 0.f;
    for(int d=s; d<256; d+=16) acc = fmaf(ir[d], w[o*256+d], acc);
    #pragma unroll
    for(int off=8; off>0; off>>=1) acc += __shfl_xor(acc, off);
    if(s == 0) out[bb*40 + o] = acc + bias[o];
}

extern "C" void kernel_launch(void* const* d_in, const int* in_sizes, int n_in,
                              void* d_out, int out_size, void* d_ws, size_t ws_size,
                              hipStream_t stream) {
    const float* x       = (const float*)d_in[0];
    const float* th[4]   = {(const float*)d_in[1], (const float*)d_in[3], (const float*)d_in[5], (const float*)d_in[7]};
    const float* ph[4]   = {(const float*)d_in[2], (const float*)d_in[4], (const float*)d_in[6], (const float*)d_in[8]};
    const float* proj_w  = (const float*)d_in[9];
    const float* proj_b  = (const float*)d_in[10];
    const float* emb0_w  = (const float*)d_in[11];
    const float* emb0_b  = (const float*)d_in[12];
    const float* bn0_g   = (const float*)d_in[13];
    const float* bn0_b   = (const float*)d_in[14];
    const float* emb1_w  = (const float*)d_in[15];
    const float* emb1_b  = (const float*)d_in[16];
    const float* bn1_g   = (const float*)d_in[17];
    const float* bn1_b   = (const float*)d_in[18];
    const float* out_w   = (const float*)d_in[19];
    const float* out_b   = (const float*)d_in[20];
    float* outp = (float*)d_out;

    // workspace layout (float elements)
    const size_t OFF_HS  = 0;                       // 16384 x 512 = 8,388,608
    const size_t OFF_T   = 8388608;                 // 16384 x 256 = 4,194,304
    const size_t OFF_U   = 12582912;                // 16384 x 256 = 4,194,304
    const size_t OFF_SQN = 16777216;                // 16384
    const size_t OFF_IDX = 16793600;                // 16384 x 20 ints = 327,680
    const size_t REQ_FL  = 17121280;
    const size_t REQ     = REQ_FL * 4;              // 68,485,120 bytes

    if(ws_size < REQ){
        fallback_k<<<(out_size+255)/256, 256, 0, stream>>>(outp, out_size, (float)((double)ws_size*1e-6));
        return;
    }

    float* Wf   = (float*)d_ws;
    float* hs   = Wf + OFF_HS;
    float* T    = Wf + OFF_T;
    float* U    = Wf + OFF_U;
    float* sqn  = Wf + OFF_SQN;
    int*   idxb = (int*)(Wf + OFF_IDX);
    // post-layer aliases inside T region (T dead after last gather)
    float* pmax   = T;
    float* psum   = T + 262144;
    float* pooled = T + 524288;
    float* z0     = T + 557056;
    float* z1     = T + 565248;

    // ---- layer 0: h=x (S=3,D=3) -> O=64 at hs ch 0
    sqnorm_k<3><<<64,256,0,stream>>>(x, 3, sqn);
    knn_k<3><<<dim3(256,16),256,0,stream>>>(x, 3, sqn, idxb);
    featTU_k<3,64><<<dim3(1,256),256,0,stream>>>(x, 3, th[0], ph[0], T, U);
    gather2_k<64><<<BB*NN/4,256,0,stream>>>(T, U, idxb, hs + 0);

    // ---- layer 1: h=hs[:,0:64] (S=512,D=64) -> O=64 at ch 64
    sqnorm_k<64><<<64,256,0,stream>>>(hs + 0, 512, sqn);
    knn_k<64><<<dim3(256,16),256,0,stream>>>(hs + 0, 512, sqn, idxb);
    featTU_k<64,64><<<dim3(1,256),256,0,stream>>>(hs + 0, 512, th[1], ph[1], T, U);
    gather2_k<64><<<BB*NN/4,256,0,stream>>>(T, U, idxb, hs + 64);

    // ---- layer 2: h=hs[:,64:128] (D=64) -> O=128 at ch 128
    sqnorm_k<64><<<64,256,0,stream>>>(hs + 64, 512, sqn);
    knn_k<64><<<dim3(256,16),256,0,stream>>>(hs + 64, 512, sqn, idxb);
    featTU_k<64,128><<<dim3(2,256),256,0,stream>>>(hs + 64, 512, th[2], ph[2], T, U);
    gather2_k<128><<<BB*NN/2,256,0,stream>>>(T, U, idxb, hs + 128);

    // ---- layer 3: h=hs[:,128:256] (D=128) -> O=256 at ch 256
    sqnorm_k<128><<<64,256,0,stream>>>(hs + 128, 512, sqn);
    knn_k<128><<<dim3(256,16),256,0,stream>>>(hs + 128, 512, sqn, idxb);
    featTU_k<128,256><<<dim3(4,256),256,0,stream>>>(hs + 128, 512, th[3], ph[3], T, U);
    gather2_k<256><<<BB*NN,256,0,stream>>>(T, U, idxb, hs + 256);

    // ---- projection + pooling
    proj_k<<<dim3(16,16,16),256,0,stream>>>(hs, proj_w, pmax, psum);
    pool_final_k<<<64,256,0,stream>>>(pmax, psum, proj_b, pooled);

    // ---- head
    head_bn_k<2048><<<512,256,0,stream>>>(pooled, emb0_w, emb0_b, bn0_g, bn0_b, z0, 512);
    head_bn_k<512><<<256,256,0,stream>>>(z0, emb1_w, emb1_b, bn1_g, bn1_b, z1, 256);
    head_out_k<<<40,256,0,stream>>>(z1, out_w, out_b, outp);
}

// Round 5
// 1507.530 us; speedup vs baseline: 1.6359x; 1.1951x over previous
//
#include <hip/hip_runtime.h>
#include <hip/hip_bf16.h>

#define BB 16
#define NN 1024
#define KNN 20

// ---------------- fallback: encode ws_size into output if workspace too small ----------------
__global__ void fallback_k(float* __restrict__ out, int n, float c){
    int i = blockIdx.x*256 + threadIdx.x;
    if(i < n) out[i] = c;
}

// ---------------- transpose x [16,1024,3] -> hT [16][3][1024] ----------------
__global__ void transpose3_k(const float* __restrict__ x, float* __restrict__ hT){
    int i = blockIdx.x*256 + threadIdx.x;
    if(i < BB*NN){
        int b = i >> 10, n = i & 1023;
        #pragma unroll
        for(int d=0; d<3; d++)
            hT[((size_t)b*3 + d)*NN + n] = x[(size_t)i*3 + d];
    }
}

// ---------------- transpose hs slice [16,1024,D @stride512] -> hT [16][D][1024] ----------------
template<int D>
__global__ __launch_bounds__(256) void transpose_k(const float* __restrict__ src,  // hs + cbase
                                                   float* __restrict__ hT){
    int nt = blockIdx.x, ct = blockIdx.y, b = blockIdx.z;
    int tid = threadIdx.x;
    __shared__ float tile[64][65];
    int n0 = nt*64, c0 = ct*64;
    for(int l=tid; l<64*64; l+=256){
        int r = l>>6, c = l&63;
        tile[r][c] = src[(size_t)(b*NN + n0 + r)*512 + c0 + c];
    }
    __syncthreads();
    for(int l=tid; l<64*64; l+=256){
        int d = l>>6, n = l&63;
        hT[((size_t)b*D + c0 + d)*NN + n0 + n] = tile[n][d];
    }
}

// ---------------- squared norms from hT (coalesced; fma chain order matches knn2_k) ----------------
template<int D>
__global__ void sqnormT_k(const float* __restrict__ hT, float* __restrict__ sqn){
    int i = blockIdx.x*256 + threadIdx.x;
    if(i < BB*NN){
        int b = i >> 10, n = i & 1023;
        const float* p = hT + (size_t)b*D*NN + n;
        float s = 0.f;
        for(int d=0; d<D; d++){ float v = p[(size_t)d*NN]; s = fmaf(v, v, s); }
        sqn[i] = s;
    }
}

// ---------------- fused dist-GEMM (register-blocked, from hT) + top-20 ----------------
// block: 16 query rows x 1024 candidates. Each thread: 16 rows x 4 m (float4 accs).
// Per k: 1 coalesced global float4 (B) + 16 broadcast ds_read_b32 (A) + 64 fma -> VALU-bound.
// Diagonal exactly 0: same ascending-d fma chain as sqnormT_k.
template<int D>
__global__ __launch_bounds__(256) void knn2_k(const float* __restrict__ hT,
                                              const float* __restrict__ sqn,
                                              int* __restrict__ idx){
    const int b   = blockIdx.y;
    const int n0  = blockIdx.x * 16;
    const int tid = threadIdx.x;
    const int lane = tid & 63;
    const int wv   = tid >> 6;

    __shared__ float rowsA[16*D];
    __shared__ float4 distb4[16*256];
    __shared__ float sqnA[16];
    float* distb = (float*)distb4;

    const float* hTb = hT + (size_t)b*D*NN;
    for(int l=tid; l<16*D; l+=256){
        int d = l >> 4, r = l & 15;
        rowsA[l] = hTb[(size_t)d*NN + n0 + r];
    }
    if(tid < 16) sqnA[tid] = sqn[b*NN + n0 + tid];
    __syncthreads();

    const float4* B4 = (const float4*)hTb;
    float4 acc[16];
    #pragma unroll
    for(int r=0;r<16;r++) acc[r] = make_float4(0.f,0.f,0.f,0.f);

    #pragma unroll 4
    for(int d=0; d<D; d++){
        float4 bv = B4[d*256 + tid];
        #pragma unroll
        for(int r=0;r<16;r++){
            float a = rowsA[d*16 + r];
            acc[r].x = fmaf(a, bv.x, acc[r].x);
            acc[r].y = fmaf(a, bv.y, acc[r].y);
            acc[r].z = fmaf(a, bv.z, acc[r].z);
            acc[r].w = fmaf(a, bv.w, acc[r].w);
        }
    }

    float4 sq4 = ((const float4*)(sqn + b*NN))[tid];
    #pragma unroll
    for(int r=0;r<16;r++){
        float sa = sqnA[r];
        float4 dv;
        dv.x = sa + sq4.x - 2.f*acc[r].x;
        dv.y = sa + sq4.y - 2.f*acc[r].y;
        dv.z = sa + sq4.z - 2.f*acc[r].z;
        dv.w = sa + sq4.w - 2.f*acc[r].w;
        distb4[r*256 + tid] = dv;
    }
    __syncthreads();

    // top-20 per row; ties -> lowest index (matches lax.top_k stability)
    for(int i=0;i<4;i++){
        const int rr = wv + 4*i;
        float v[16];
        const float4* d4p = (const float4*)(distb + rr*1024);
        #pragma unroll
        for(int q=0;q<4;q++){
            float4 f = d4p[lane + 64*q];
            v[4*q+0]=f.x; v[4*q+1]=f.y; v[4*q+2]=f.z; v[4*q+3]=f.w;
        }
        int* out = idx + ((size_t)b*NN + n0 + rr)*KNN;
        const float FMAXV = 3.402823466e38f;
        for(int t=0;t<KNN;t++){
            float bvv = FMAXV; int bi = 0x7fffffff;
            #pragma unroll
            for(int q=0;q<16;q++){
                if(v[q] < bvv){ bvv = v[q]; bi = 4*(lane + 64*(q>>2)) + (q&3); }
            }
            #pragma unroll
            for(int off=32; off>0; off>>=1){
                float ov = __shfl_xor(bvv, off);
                int   oi = __shfl_xor(bi, off);
                if(ov < bvv || (ov == bvv && oi < bi)){ bvv = ov; bi = oi; }
            }
            if(lane == 0) out[t] = bi;
            int ol = (bi >> 2) & 63;
            if(lane == ol){
                int q = ((bi >> 8) << 2) | (bi & 3);
                v[q] = FMAXV;
            }
        }
    }
}

// ---------------- tiled dual GEMM: T = h@theta^T ; U = h@(phi-theta)^T ----------------
template<int D, int O>
__global__ __launch_bounds__(256) void featTU_k(const float* __restrict__ h, int S,
                                                const float* __restrict__ th,
                                                const float* __restrict__ ph,
                                                float* __restrict__ T, float* __restrict__ U){
    int ot = blockIdx.x, nt = blockIdx.y;
    int tid = threadIdx.x, tx = tid & 15, ty = tid >> 4;
    __shared__ float As[64][33];
    __shared__ float Wt[64][33];
    __shared__ float Wp[64][33];
    float acct[4][4] = {};
    float accp[4][4] = {};
    for(int kk=0; kk<D; kk+=32){
        for(int l=tid; l<64*32; l+=256){
            int r = l>>5, c = l&31, d = kk + c;
            As[r][c] = (d < D) ? h[(size_t)(nt*64+r)*S + d] : 0.f;
            Wt[r][c] = (d < D) ? th[(size_t)(ot*64+r)*D + d] : 0.f;
            Wp[r][c] = (d < D) ? ph[(size_t)(ot*64+r)*D + d] : 0.f;
        }
        __syncthreads();
        #pragma unroll
        for(int k=0;k<32;k++){
            float a[4], bt[4], bp[4];
            #pragma unroll
            for(int i=0;i<4;i++) a[i]  = As[ty+16*i][k];
            #pragma unroll
            for(int j=0;j<4;j++){ bt[j] = Wt[tx+16*j][k]; bp[j] = Wp[tx+16*j][k]; }
            #pragma unroll
            for(int i=0;i<4;i++)
                #pragma unroll
                for(int j=0;j<4;j++){
                    acct[i][j] = fmaf(a[i], bt[j], acct[i][j]);
                    accp[i][j] = fmaf(a[i], bp[j], accp[i][j]);
                }
        }
        __syncthreads();
    }
    #pragma unroll
    for(int i=0;i<4;i++){
        int rw = nt*64 + ty + 16*i;
        #pragma unroll
        for(int j=0;j<4;j++){
            int o = ot*64 + tx + 16*j;
            T[(size_t)rw*O + o] = acct[i][j];
            U[(size_t)rw*O + o] = accp[i][j] - acct[i][j];
        }
    }
}

// ---------------- gather 20 neighbors of T, max, + U, leaky ----------------
template<int O>
__global__ __launch_bounds__(256) void gather2_k(const float* __restrict__ T, const float* __restrict__ U,
                                                 const int* __restrict__ idx, float* __restrict__ outp){
    constexpr int P = 256 / O;           // points per block
    int bn0 = blockIdx.x * P;
    int tid = threadIdx.x;
    int p = tid / O, o = tid % O;
    int bn = bn0 + p;
    int b  = bn >> 10;
    __shared__ int nb[P*KNN];
    if(tid < P*KNN){
        int pp = tid / KNN, k = tid % KNN;
        nb[pp*KNN + k] = idx[(size_t)(bn0+pp)*KNN + k] & (NN-1);  // mask: never faults
    }
    __syncthreads();
    const float* Tb = T + (size_t)b*NN*O;
    float m = -3.402823466e38f;
    #pragma unroll
    for(int k=0;k<KNN;k++) m = fmaxf(m, Tb[(size_t)nb[p*KNN+k]*O + o]);
    float v = m + U[(size_t)bn*O + o];
    v = (v > 0.f) ? v : 0.2f*v;
    outp[(size_t)bn*512 + o] = v;
}

// ---------------- projection GEMM (16K x 512 x 1024) with fused partial max/sum pool ----------------
__global__ __launch_bounds__(256) void proj_k(const float* __restrict__ hs, const float* __restrict__ w,
                                              float* __restrict__ pmax, float* __restrict__ psum){
    int ot = blockIdx.x, nt = blockIdx.y, b = blockIdx.z;
    int tid = threadIdx.x;
    int tx = tid & 15, ty = tid >> 4;
    __shared__ float As[64][33];
    __shared__ float Ws[64][33];
    __shared__ float red[16][64];
    float acc[4][4] = {};
    const float* hb = hs + (size_t)b*NN*512;
    for(int kk=0; kk<512; kk+=32){
        for(int l=tid; l<64*32; l+=256){
            int r = l>>5, c = l&31;
            As[r][c] = hb[(size_t)(nt*64+r)*512 + kk + c];
            Ws[r][c] = w[(size_t)(ot*64+r)*512 + kk + c];
        }
        __syncthreads();
        #pragma unroll
        for(int k=0;k<32;k++){
            float a[4], bv[4];
            #pragma unroll
            for(int i=0;i<4;i++) a[i]  = As[ty+16*i][k];
            #pragma unroll
            for(int j=0;j<4;j++) bv[j] = Ws[tx+16*j][k];
            #pragma unroll
            for(int i=0;i<4;i++)
                #pragma unroll
                for(int j=0;j<4;j++) acc[i][j] = fmaf(a[i], bv[j], acc[i][j]);
        }
        __syncthreads();
    }
    float tmax[4], tsum[4];
    #pragma unroll
    for(int j=0;j<4;j++){
        tmax[j] = acc[0][j]; tsum[j] = acc[0][j];
        #pragma unroll
        for(int i=1;i<4;i++){ tmax[j] = fmaxf(tmax[j], acc[i][j]); tsum[j] += acc[i][j]; }
    }
    #pragma unroll
    for(int j=0;j<4;j++) red[ty][tx+16*j] = tmax[j];
    __syncthreads();
    if(tid < 64){
        float m = red[0][tid];
        for(int r=1;r<16;r++) m = fmaxf(m, red[r][tid]);
        pmax[((size_t)b*16 + nt)*1024 + ot*64 + tid] = m;
    }
    __syncthreads();
    #pragma unroll
    for(int j=0;j<4;j++) red[ty][tx+16*j] = tsum[j];
    __syncthreads();
    if(tid < 64){
        float s = 0.f;
        for(int r=0;r<16;r++) s += red[r][tid];
        psum[((size_t)b*16 + nt)*1024 + ot*64 + tid] = s;
    }
}

// ---------------- combine n-tiles, add bias -> pooled [16, 2048] (max | mean) ----------------
__global__ void pool_final_k(const float* __restrict__ pmax, const float* __restrict__ psum,
                             const float* __restrict__ pb, float* __restrict__ pooled){
    int i = blockIdx.x*256 + threadIdx.x;   // b*1024 + o
    if(i >= BB*1024) return;
    int b = i >> 10, o = i & 1023;
    float m = -3.402823466e38f, s = 0.f;
    for(int t=0;t<16;t++){
        m = fmaxf(m, pmax[((size_t)b*16 + t)*1024 + o]);
        s += psum[((size_t)b*16 + t)*1024 + o];
    }
    float bias = pb[o];
    pooled[b*2048 + o]        = m + bias;
    pooled[b*2048 + 1024 + o] = s * (1.f/1024.f) + bias;
}

// ---------------- head FC + BatchNorm(batch of 16) + leaky; one block per feature ----------------
template<int IN>
__global__ __launch_bounds__(256) void head_bn_k(const float* __restrict__ in, const float* __restrict__ w,
                                                 const float* __restrict__ bias, const float* __restrict__ g,
                                                 const float* __restrict__ bt, float* __restrict__ out, int OUT){
    int o = blockIdx.x;
    int tid = threadIdx.x, bb = tid >> 4, s = tid & 15;
    const float* ir = in + (size_t)bb*IN;
    const float* wr = w  + (size_t)o*IN;
    float acc = 0.f;
    for(int d=s; d<IN; d+=16) acc = fmaf(ir[d], wr[d], acc);
    #pragma unroll
    for(int off=8; off>0; off>>=1) acc += __shfl_xor(acc, off);
    __shared__ float vals[16];
    __shared__ float stats[2];
    if(s == 0) vals[bb] = acc + bias[o];
    __syncthreads();
    if(tid == 0){
        float mu = 0.f;
        for(int q=0;q<16;q++) mu += vals[q];
        mu *= (1.f/16.f);
        float var = 0.f;
        for(int q=0;q<16;q++){ float d = vals[q]-mu; var = fmaf(d,d,var); }
        var *= (1.f/16.f);
        stats[0] = mu; stats[1] = rsqrtf(var + 1e-5f);
    }
    __syncthreads();
    if(s == 0){
        float v = (vals[bb]-stats[0])*stats[1]*g[o] + bt[o];
        v = (v > 0.f) ? v : 0.2f*v;
        out[(size_t)bb*OUT + o] = v;
    }
}

// ---------------- final linear -> f32 out [16,40] ----------------
__global__ __launch_bounds__(256) void head_out_k(const float* __restrict__ in, const float* __restrict__ w,
                                                  const float* __restrict__ bias, float* __restrict__ out){
    int o = blockIdx.x;   // 40
    int tid = threadIdx.x, bb = tid >> 4, s = tid & 15;
    const float* ir = in + (size_t)bb*256;
    float acc = 0.f;
    for(int d=s; d<256; d+=16) acc = fmaf(ir[d], w[o*256+d], acc);
    #pragma unroll
    for(int off=8; off>0; off>>=1) acc += __shfl_xor(acc, off);
    if(s == 0) out[bb*40 + o] = acc + bias[o];
}

extern "C" void kernel_launch(void* const* d_in, const int* in_sizes, int n_in,
                              void* d_out, int out_size, void* d_ws, size_t ws_size,
                              hipStream_t stream) {
    const float* x       = (const float*)d_in[0];
    const float* th[4]   = {(const float*)d_in[1], (const float*)d_in[3], (const float*)d_in[5], (const float*)d_in[7]};
    const float* ph[4]   = {(const float*)d_in[2], (const float*)d_in[4], (const float*)d_in[6], (const float*)d_in[8]};
    const float* proj_w  = (const float*)d_in[9];
    const float* proj_b  = (const float*)d_in[10];
    const float* emb0_w  = (const float*)d_in[11];
    const float* emb0_b  = (const float*)d_in[12];
    const float* bn0_g   = (const float*)d_in[13];
    const float* bn0_b   = (const float*)d_in[14];
    const float* emb1_w  = (const float*)d_in[15];
    const float* emb1_b  = (const float*)d_in[16];
    const float* bn1_g   = (const float*)d_in[17];
    const float* bn1_b   = (const float*)d_in[18];
    const float* out_w   = (const float*)d_in[19];
    const float* out_b   = (const float*)d_in[20];
    float* outp = (float*)d_out;

    // workspace layout (float elements) — unchanged from round 4 (guard passed at 68.5 MB)
    const size_t OFF_HS  = 0;                       // 16384 x 512 = 8,388,608
    const size_t OFF_T   = 8388608;                 // 16384 x 256 = 4,194,304
    const size_t OFF_U   = 12582912;                // 16384 x 256 = 4,194,304
    const size_t OFF_SQN = 16777216;                // 16384
    const size_t OFF_IDX = 16793600;                // 16384 x 20 ints = 327,680
    const size_t REQ_FL  = 17121280;
    const size_t REQ     = REQ_FL * 4;              // 68,485,120 bytes

    if(ws_size < REQ){
        fallback_k<<<(out_size+255)/256, 256, 0, stream>>>(outp, out_size, (float)((double)ws_size*1e-6));
        return;
    }

    float* Wf   = (float*)d_ws;
    float* hs   = Wf + OFF_HS;
    float* T    = Wf + OFF_T;
    float* U    = Wf + OFF_U;
    float* sqn  = Wf + OFF_SQN;
    int*   idxb = (int*)(Wf + OFF_IDX);
    // hT aliases T region (max 16x128x1024 = 8 MB <= 16 MB); hT dead before featTU writes T
    float* hT   = T;
    // post-layer aliases inside T region (dead after last gather)
    float* pmax   = T;
    float* psum   = T + 262144;
    float* pooled = T + 524288;
    float* z0     = T + 557056;
    float* z1     = T + 565248;

    // ---- layer 0: h=x (S=3,D=3) -> O=64 at hs ch 0
    transpose3_k<<<64,256,0,stream>>>(x, hT);
    sqnormT_k<3><<<64,256,0,stream>>>(hT, sqn);
    knn2_k<3><<<dim3(64,16),256,0,stream>>>(hT, sqn, idxb);
    featTU_k<3,64><<<dim3(1,256),256,0,stream>>>(x, 3, th[0], ph[0], T, U);
    gather2_k<64><<<BB*NN/4,256,0,stream>>>(T, U, idxb, hs + 0);

    // ---- layer 1: h=hs[:,0:64] (S=512,D=64) -> O=64 at ch 64
    transpose_k<64><<<dim3(16,1,16),256,0,stream>>>(hs + 0, hT);
    sqnormT_k<64><<<64,256,0,stream>>>(hT, sqn);
    knn2_k<64><<<dim3(64,16),256,0,stream>>>(hT, sqn, idxb);
    featTU_k<64,64><<<dim3(1,256),256,0,stream>>>(hs + 0, 512, th[1], ph[1], T, U);
    gather2_k<64><<<BB*NN/4,256,0,stream>>>(T, U, idxb, hs + 64);

    // ---- layer 2: h=hs[:,64:128] (D=64) -> O=128 at ch 128
    transpose_k<64><<<dim3(16,1,16),256,0,stream>>>(hs + 64, hT);
    sqnormT_k<64><<<64,256,0,stream>>>(hT, sqn);
    knn2_k<64><<<dim3(64,16),256,0,stream>>>(hT, sqn, idxb);
    featTU_k<64,128><<<dim3(2,256),256,0,stream>>>(hs + 64, 512, th[2], ph[2], T, U);
    gather2_k<128><<<BB*NN/2,256,0,stream>>>(T, U, idxb, hs + 128);

    // ---- layer 3: h=hs[:,128:256] (D=128) -> O=256 at ch 256
    transpose_k<128><<<dim3(16,2,16),256,0,stream>>>(hs + 128, hT);
    sqnormT_k<128><<<64,256,0,stream>>>(hT, sqn);
    knn2_k<128><<<dim3(64,16),256,0,stream>>>(hT, sqn, idxb);
    featTU_k<128,256><<<dim3(4,256),256,0,stream>>>(hs + 128, 512, th[3], ph[3], T, U);
    gather2_k<256><<<BB*NN,256,0,stream>>>(T, U, idxb, hs + 256);

    // ---- projection + pooling
    proj_k<<<dim3(16,16,16),256,0,stream>>>(hs, proj_w, pmax, psum);
    pool_final_k<<<64,256,0,stream>>>(pmax, psum, proj_b, pooled);

    // ---- head
    head_bn_k<2048><<<512,256,0,stream>>>(pooled, emb0_w, emb0_b, bn0_g, bn0_b, z0, 512);
    head_bn_k<512><<<256,256,0,stream>>>(z0, emb1_w, emb1_b, bn1_g, bn1_b, z1, 256);
    head_out_k<<<40,256,0,stream>>>(z1, out_w, out_b, outp);
}

// Round 6
// 1323.554 us; speedup vs baseline: 1.8632x; 1.1390x over previous
//
#include <hip/hip_runtime.h>
#include <hip/hip_bf16.h>

#define BB 16
#define NN 1024
#define KNN 20

// ---------------- fallback: encode ws_size into output if workspace too small ----------------
__global__ void fallback_k(float* __restrict__ out, int n, float c){
    int i = blockIdx.x*256 + threadIdx.x;
    if(i < n) out[i] = c;
}

// ---------------- transpose x [16,1024,3] -> hT [16][3][1024] ----------------
__global__ void transpose3_k(const float* __restrict__ x, float* __restrict__ hT){
    int i = blockIdx.x*256 + threadIdx.x;
    if(i < BB*NN){
        int b = i >> 10, n = i & 1023;
        #pragma unroll
        for(int d=0; d<3; d++)
            hT[((size_t)b*3 + d)*NN + n] = x[(size_t)i*3 + d];
    }
}

// ---------------- transpose hs slice [16,1024,D @stride512] -> hT [16][D][1024] ----------------
template<int D>
__global__ __launch_bounds__(256) void transpose_k(const float* __restrict__ src,  // hs + cbase
                                                   float* __restrict__ hT){
    int nt = blockIdx.x, ct = blockIdx.y, b = blockIdx.z;
    int tid = threadIdx.x;
    __shared__ float tile[64][65];
    int n0 = nt*64, c0 = ct*64;
    for(int l=tid; l<64*64; l+=256){
        int r = l>>6, c = l&63;
        tile[r][c] = src[(size_t)(b*NN + n0 + r)*512 + c0 + c];
    }
    __syncthreads();
    for(int l=tid; l<64*64; l+=256){
        int d = l>>6, n = l&63;
        hT[((size_t)b*D + c0 + d)*NN + n0 + n] = tile[n][d];
    }
}

// ---------------- squared norms from hT (coalesced; fma chain order matches knn2_k) ----------------
template<int D>
__global__ void sqnormT_k(const float* __restrict__ hT, float* __restrict__ sqn){
    int i = blockIdx.x*256 + threadIdx.x;
    if(i < BB*NN){
        int b = i >> 10, n = i & 1023;
        const float* p = hT + (size_t)b*D*NN + n;
        float s = 0.f;
        for(int d=0; d<D; d++){ float v = p[(size_t)d*NN]; s = fmaf(v, v, s); }
        sqn[i] = s;
    }
}

// ---------------- fused dist-GEMM (register-blocked, from hT) + top-20 ----------------
template<int D>
__global__ __launch_bounds__(256) void knn2_k(const float* __restrict__ hT,
                                              const float* __restrict__ sqn,
                                              int* __restrict__ idx){
    const int b   = blockIdx.y;
    const int n0  = blockIdx.x * 16;
    const int tid = threadIdx.x;
    const int lane = tid & 63;
    const int wv   = tid >> 6;

    __shared__ float rowsA[16*D];
    __shared__ float4 distb4[16*256];
    __shared__ float sqnA[16];
    float* distb = (float*)distb4;

    const float* hTb = hT + (size_t)b*D*NN;
    for(int l=tid; l<16*D; l+=256){
        int d = l >> 4, r = l & 15;
        rowsA[l] = hTb[(size_t)d*NN + n0 + r];
    }
    if(tid < 16) sqnA[tid] = sqn[b*NN + n0 + tid];
    __syncthreads();

    const float4* B4 = (const float4*)hTb;
    float4 acc[16];
    #pragma unroll
    for(int r=0;r<16;r++) acc[r] = make_float4(0.f,0.f,0.f,0.f);

    #pragma unroll 4
    for(int d=0; d<D; d++){
        float4 bv = B4[d*256 + tid];
        #pragma unroll
        for(int r=0;r<16;r++){
            float a = rowsA[d*16 + r];
            acc[r].x = fmaf(a, bv.x, acc[r].x);
            acc[r].y = fmaf(a, bv.y, acc[r].y);
            acc[r].z = fmaf(a, bv.z, acc[r].z);
            acc[r].w = fmaf(a, bv.w, acc[r].w);
        }
    }

    float4 sq4 = ((const float4*)(sqn + b*NN))[tid];
    #pragma unroll
    for(int r=0;r<16;r++){
        float sa = sqnA[r];
        float4 dv;
        dv.x = sa + sq4.x - 2.f*acc[r].x;
        dv.y = sa + sq4.y - 2.f*acc[r].y;
        dv.z = sa + sq4.z - 2.f*acc[r].z;
        dv.w = sa + sq4.w - 2.f*acc[r].w;
        distb4[r*256 + tid] = dv;
    }
    __syncthreads();

    // top-20 per row; ties -> lowest index (matches lax.top_k stability)
    for(int i=0;i<4;i++){
        const int rr = wv + 4*i;
        float v[16];
        const float4* d4p = (const float4*)(distb + rr*1024);
        #pragma unroll
        for(int q=0;q<4;q++){
            float4 f = d4p[lane + 64*q];
            v[4*q+0]=f.x; v[4*q+1]=f.y; v[4*q+2]=f.z; v[4*q+3]=f.w;
        }
        int* out = idx + ((size_t)b*NN + n0 + rr)*KNN;
        const float FMAXV = 3.402823466e38f;
        for(int t=0;t<KNN;t++){
            float bvv = FMAXV; int bi = 0x7fffffff;
            #pragma unroll
            for(int q=0;q<16;q++){
                if(v[q] < bvv){ bvv = v[q]; bi = 4*(lane + 64*(q>>2)) + (q&3); }
            }
            #pragma unroll
            for(int off=32; off>0; off>>=1){
                float ov = __shfl_xor(bvv, off);
                int   oi = __shfl_xor(bi, off);
                if(ov < bvv || (ov == bvv && oi < bi)){ bvv = ov; bi = oi; }
            }
            if(lane == 0) out[t] = bi;
            int ol = (bi >> 2) & 63;
            if(lane == ol){
                int q = ((bi >> 8) << 2) | (bi & 3);
                v[q] = FMAXV;
            }
        }
    }
}

// ---------------- tiled dual GEMM: T = h@theta^T ; U = h@(phi-theta)^T ----------------
template<int D, int O>
__global__ __launch_bounds__(256) void featTU_k(const float* __restrict__ h, int S,
                                                const float* __restrict__ th,
                                                const float* __restrict__ ph,
                                                float* __restrict__ T, float* __restrict__ U){
    int ot = blockIdx.x, nt = blockIdx.y;
    int tid = threadIdx.x, tx = tid & 15, ty = tid >> 4;
    __shared__ float As[64][33];
    __shared__ float Wt[64][33];
    __shared__ float Wp[64][33];
    float acct[4][4] = {};
    float accp[4][4] = {};
    for(int kk=0; kk<D; kk+=32){
        for(int l=tid; l<64*32; l+=256){
            int r = l>>5, c = l&31, d = kk + c;
            As[r][c] = (d < D) ? h[(size_t)(nt*64+r)*S + d] : 0.f;
            Wt[r][c] = (d < D) ? th[(size_t)(ot*64+r)*D + d] : 0.f;
            Wp[r][c] = (d < D) ? ph[(size_t)(ot*64+r)*D + d] : 0.f;
        }
        __syncthreads();
        #pragma unroll
        for(int k=0;k<32;k++){
            float a[4], bt[4], bp[4];
            #pragma unroll
            for(int i=0;i<4;i++) a[i]  = As[ty+16*i][k];
            #pragma unroll
            for(int j=0;j<4;j++){ bt[j] = Wt[tx+16*j][k]; bp[j] = Wp[tx+16*j][k]; }
            #pragma unroll
            for(int i=0;i<4;i++)
                #pragma unroll
                for(int j=0;j<4;j++){
                    acct[i][j] = fmaf(a[i], bt[j], acct[i][j]);
                    accp[i][j] = fmaf(a[i], bp[j], accp[i][j]);
                }
        }
        __syncthreads();
    }
    #pragma unroll
    for(int i=0;i<4;i++){
        int rw = nt*64 + ty + 16*i;
        #pragma unroll
        for(int j=0;j<4;j++){
            int o = ot*64 + tx + 16*j;
            T[(size_t)rw*O + o] = acct[i][j];
            U[(size_t)rw*O + o] = accp[i][j] - acct[i][j];
        }
    }
}

// ---------------- gather 20 neighbors of T, max, + U, leaky ----------------
template<int O>
__global__ __launch_bounds__(256) void gather2_k(const float* __restrict__ T, const float* __restrict__ U,
                                                 const int* __restrict__ idx, float* __restrict__ outp){
    constexpr int P = 256 / O;           // points per block
    int bn0 = blockIdx.x * P;
    int tid = threadIdx.x;
    int p = tid / O, o = tid % O;
    int bn = bn0 + p;
    int b  = bn >> 10;
    __shared__ int nb[P*KNN];
    if(tid < P*KNN){
        int pp = tid / KNN, k = tid % KNN;
        nb[pp*KNN + k] = idx[(size_t)(bn0+pp)*KNN + k] & (NN-1);  // mask: never faults
    }
    __syncthreads();
    const float* Tb = T + (size_t)b*NN*O;
    float m = -3.402823466e38f;
    #pragma unroll
    for(int k=0;k<KNN;k++) m = fmaxf(m, Tb[(size_t)nb[p*KNN+k]*O + o]);
    float v = m + U[(size_t)bn*O + o];
    v = (v > 0.f) ? v : 0.2f*v;
    outp[(size_t)bn*512 + o] = v;
}

// ---------------- projection GEMM: 128x128 tile, 8x8/thread, max-pool epilogue only ----------------
__global__ __launch_bounds__(256) void proj2_k(const float* __restrict__ hs, const float* __restrict__ w,
                                               float* __restrict__ pmax){
    int ot = blockIdx.x;          // 8 col tiles of 128
    int nt = blockIdx.y;          // 8 row tiles of 128 (within batch)
    int b  = blockIdx.z;          // 16
    int tid = threadIdx.x;
    int tx = tid & 15, ty = tid >> 4;
    __shared__ float As[16][132];     // [k][row], padded
    __shared__ float Ws[16][132];     // [k][col]
    __shared__ float red[16][128];
    float acc[8][8] = {};
    const float* ha = hs + ((size_t)b*NN + (size_t)nt*128)*512;
    const float* wa = w + (size_t)ot*128*512;
    for(int kk=0; kk<512; kk+=16){
        __syncthreads();
        #pragma unroll
        for(int q=0; q<2; q++){
            int idx = tid + 256*q;          // 0..511: r=idx>>2 (128 rows), c0=4*(idx&3)
            int r = idx >> 2, c0 = (idx & 3)*4;
            float4 av = *(const float4*)&ha[(size_t)r*512 + kk + c0];
            float4 wv = *(const float4*)&wa[(size_t)r*512 + kk + c0];
            As[c0+0][r] = av.x; As[c0+1][r] = av.y; As[c0+2][r] = av.z; As[c0+3][r] = av.w;
            Ws[c0+0][r] = wv.x; Ws[c0+1][r] = wv.y; Ws[c0+2][r] = wv.z; Ws[c0+3][r] = wv.w;
        }
        __syncthreads();
        #pragma unroll
        for(int k=0;k<16;k++){
            float a[8], bv[8];
            *(float4*)&a[0]  = *(const float4*)&As[k][ty*8];
            *(float4*)&a[4]  = *(const float4*)&As[k][ty*8+4];
            *(float4*)&bv[0] = *(const float4*)&Ws[k][tx*8];
            *(float4*)&bv[4] = *(const float4*)&Ws[k][tx*8+4];
            #pragma unroll
            for(int i=0;i<8;i++)
                #pragma unroll
                for(int j=0;j<8;j++) acc[i][j] = fmaf(a[i], bv[j], acc[i][j]);
        }
    }
    float cmax[8];
    #pragma unroll
    for(int j=0;j<8;j++){
        cmax[j] = acc[0][j];
        #pragma unroll
        for(int i=1;i<8;i++) cmax[j] = fmaxf(cmax[j], acc[i][j]);
    }
    __syncthreads();
    #pragma unroll
    for(int j=0;j<8;j++) red[ty][tx*8+j] = cmax[j];
    __syncthreads();
    if(tid < 128){
        float m = red[0][tid];
        #pragma unroll
        for(int r=1;r<16;r++) m = fmaxf(m, red[r][tid]);
        pmax[((size_t)b*8 + nt)*1024 + ot*128 + tid] = m;
    }
}

// ---------------- column sums of hs: colsum[16][512] (for algebraic mean-pool) ----------------
__global__ void colsum_k(const float* __restrict__ hs, float* __restrict__ colsum){
    int i = blockIdx.x*256 + threadIdx.x;   // b*512 + c
    if(i >= BB*512) return;
    int b = i >> 9, c = i & 511;
    const float* p = hs + (size_t)b*NN*512 + c;
    float s = 0.f;
    for(int n=0;n<NN;n++) s += p[(size_t)n*512];
    colsum[i] = s;
}

// ---------------- combine: max over 8 tiles; mean = colsum@w/1024; + bias ----------------
__global__ __launch_bounds__(256) void pool_final2_k(const float* __restrict__ pmax,
                                                     const float* __restrict__ colsum,
                                                     const float* __restrict__ w,
                                                     const float* __restrict__ pb,
                                                     float* __restrict__ pooled){
    int i = blockIdx.x*256 + threadIdx.x;   // b*1024 + o (block covers one b)
    int b = i >> 10, o = i & 1023;
    __shared__ float cs[512];
    for(int l=threadIdx.x; l<512; l+=256) cs[l] = colsum[b*512 + l];
    __syncthreads();
    float m = -3.402823466e38f;
    #pragma unroll
    for(int t=0;t<8;t++) m = fmaxf(m, pmax[((size_t)b*8 + t)*1024 + o]);
    float s = 0.f;
    const float4* w4 = (const float4*)(w + (size_t)o*512);
    const float4* c4 = (const float4*)cs;
    for(int d=0; d<128; d++){
        float4 wv = w4[d]; float4 cv = c4[d];
        s = fmaf(cv.x, wv.x, s); s = fmaf(cv.y, wv.y, s);
        s = fmaf(cv.z, wv.z, s); s = fmaf(cv.w, wv.w, s);
    }
    float bias = pb[o];
    pooled[b*2048 + o]        = m + bias;
    pooled[b*2048 + 1024 + o] = s * (1.f/1024.f) + bias;
}

// ---------------- head FC + BatchNorm(batch of 16) + leaky; one block per feature ----------------
template<int IN>
__global__ __launch_bounds__(256) void head_bn_k(const float* __restrict__ in, const float* __restrict__ w,
                                                 const float* __restrict__ bias, const float* __restrict__ g,
                                                 const float* __restrict__ bt, float* __restrict__ out, int OUT){
    int o = blockIdx.x;
    int tid = threadIdx.x, bb = tid >> 4, s = tid & 15;
    const float* ir = in + (size_t)bb*IN;
    const float* wr = w  + (size_t)o*IN;
    float acc = 0.f;
    for(int d=s; d<IN; d+=16) acc = fmaf(ir[d], wr[d], acc);
    #pragma unroll
    for(int off=8; off>0; off>>=1) acc += __shfl_xor(acc, off);
    __shared__ float vals[16];
    __shared__ float stats[2];
    if(s == 0) vals[bb] = acc + bias[o];
    __syncthreads();
    if(tid == 0){
        float mu = 0.f;
        for(int q=0;q<16;q++) mu += vals[q];
        mu *= (1.f/16.f);
        float var = 0.f;
        for(int q=0;q<16;q++){ float d = vals[q]-mu; var = fmaf(d,d,var); }
        var *= (1.f/16.f);
        stats[0] = mu; stats[1] = rsqrtf(var + 1e-5f);
    }
    __syncthreads();
    if(s == 0){
        float v = (vals[bb]-stats[0])*stats[1]*g[o] + bt[o];
        v = (v > 0.f) ? v : 0.2f*v;
        out[(size_t)bb*OUT + o] = v;
    }
}

// ---------------- final linear -> f32 out [16,40] ----------------
__global__ __launch_bounds__(256) void head_out_k(const float* __restrict__ in, const float* __restrict__ w,
                                                  const float* __restrict__ bias, float* __restrict__ out){
    int o = blockIdx.x;   // 40
    int tid = threadIdx.x, bb = tid >> 4, s = tid & 15;
    const float* ir = in + (size_t)bb*256;
    float acc = 0.f;
    for(int d=s; d<256; d+=16) acc = fmaf(ir[d], w[o*256+d], acc);
    #pragma unroll
    for(int off=8; off>0; off>>=1) acc += __shfl_xor(acc, off);
    if(s == 0) out[bb*40 + o] = acc + bias[o];
}

extern "C" void kernel_launch(void* const* d_in, const int* in_sizes, int n_in,
                              void* d_out, int out_size, void* d_ws, size_t ws_size,
                              hipStream_t stream) {
    const float* x       = (const float*)d_in[0];
    const float* th[4]   = {(const float*)d_in[1], (const float*)d_in[3], (const float*)d_in[5], (const float*)d_in[7]};
    const float* ph[4]   = {(const float*)d_in[2], (const float*)d_in[4], (const float*)d_in[6], (const float*)d_in[8]};
    const float* proj_w  = (const float*)d_in[9];
    const float* proj_b  = (const float*)d_in[10];
    const float* emb0_w  = (const float*)d_in[11];
    const float* emb0_b  = (const float*)d_in[12];
    const float* bn0_g   = (const float*)d_in[13];
    const float* bn0_b   = (const float*)d_in[14];
    const float* emb1_w  = (const float*)d_in[15];
    const float* emb1_b  = (const float*)d_in[16];
    const float* bn1_g   = (const float*)d_in[17];
    const float* bn1_b   = (const float*)d_in[18];
    const float* out_w   = (const float*)d_in[19];
    const float* out_b   = (const float*)d_in[20];
    float* outp = (float*)d_out;

    // workspace layout (float elements) — unchanged from round 4/5 (guard passed at 68.5 MB)
    const size_t OFF_HS  = 0;                       // 16384 x 512 = 8,388,608
    const size_t OFF_T   = 8388608;                 // 16384 x 256 = 4,194,304
    const size_t OFF_U   = 12582912;                // 16384 x 256 = 4,194,304
    const size_t OFF_SQN = 16777216;                // 16384
    const size_t OFF_IDX = 16793600;                // 16384 x 20 ints = 327,680
    const size_t REQ_FL  = 17121280;
    const size_t REQ     = REQ_FL * 4;              // 68,485,120 bytes

    if(ws_size < REQ){
        fallback_k<<<(out_size+255)/256, 256, 0, stream>>>(outp, out_size, (float)((double)ws_size*1e-6));
        return;
    }

    float* Wf   = (float*)d_ws;
    float* hs   = Wf + OFF_HS;
    float* T    = Wf + OFF_T;
    float* U    = Wf + OFF_U;
    float* sqn  = Wf + OFF_SQN;
    int*   idxb = (int*)(Wf + OFF_IDX);
    // hT aliases T region (max 16x128x1024 = 8 MB <= 16 MB); hT dead before featTU writes T
    float* hT   = T;
    // post-layer aliases inside T region (dead after last gather)
    float* pmax   = T;                 // 16*8*1024 = 131072
    float* colsum = T + 131072;        // 16*512   = 8192
    float* pooled = T + 147456;        // 16*2048  = 32768
    float* z0     = T + 180224;        // 16*512
    float* z1     = T + 188416;        // 16*256

    // ---- layer 0: h=x (S=3,D=3) -> O=64 at hs ch 0
    transpose3_k<<<64,256,0,stream>>>(x, hT);
    sqnormT_k<3><<<64,256,0,stream>>>(hT, sqn);
    knn2_k<3><<<dim3(64,16),256,0,stream>>>(hT, sqn, idxb);
    featTU_k<3,64><<<dim3(1,256),256,0,stream>>>(x, 3, th[0], ph[0], T, U);
    gather2_k<64><<<BB*NN/4,256,0,stream>>>(T, U, idxb, hs + 0);

    // ---- layer 1: h=hs[:,0:64] (S=512,D=64) -> O=64 at ch 64
    transpose_k<64><<<dim3(16,1,16),256,0,stream>>>(hs + 0, hT);
    sqnormT_k<64><<<64,256,0,stream>>>(hT, sqn);
    knn2_k<64><<<dim3(64,16),256,0,stream>>>(hT, sqn, idxb);
    featTU_k<64,64><<<dim3(1,256),256,0,stream>>>(hs + 0, 512, th[1], ph[1], T, U);
    gather2_k<64><<<BB*NN/4,256,0,stream>>>(T, U, idxb, hs + 64);

    // ---- layer 2: h=hs[:,64:128] (D=64) -> O=128 at ch 128
    transpose_k<64><<<dim3(16,1,16),256,0,stream>>>(hs + 64, hT);
    sqnormT_k<64><<<64,256,0,stream>>>(hT, sqn);
    knn2_k<64><<<dim3(64,16),256,0,stream>>>(hT, sqn, idxb);
    featTU_k<64,128><<<dim3(2,256),256,0,stream>>>(hs + 64, 512, th[2], ph[2], T, U);
    gather2_k<128><<<BB*NN/2,256,0,stream>>>(T, U, idxb, hs + 128);

    // ---- layer 3: h=hs[:,128:256] (D=128) -> O=256 at ch 256
    transpose_k<128><<<dim3(16,2,16),256,0,stream>>>(hs + 128, hT);
    sqnormT_k<128><<<64,256,0,stream>>>(hT, sqn);
    knn2_k<128><<<dim3(64,16),256,0,stream>>>(hT, sqn, idxb);
    featTU_k<128,256><<<dim3(4,256),256,0,stream>>>(hs + 128, 512, th[3], ph[3], T, U);
    gather2_k<256><<<BB*NN,256,0,stream>>>(T, U, idxb, hs + 256);

    // ---- projection + pooling (max via tiled GEMM; mean via colsum @ w)
    proj2_k<<<dim3(8,8,16),256,0,stream>>>(hs, proj_w, pmax);
    colsum_k<<<32,256,0,stream>>>(hs, colsum);
    pool_final2_k<<<64,256,0,stream>>>(pmax, colsum, proj_w, proj_b, pooled);

    // ---- head
    head_bn_k<2048><<<512,256,0,stream>>>(pooled, emb0_w, emb0_b, bn0_g, bn0_b, z0, 512);
    head_bn_k<512><<<256,256,0,stream>>>(z0, emb1_w, emb1_b, bn1_g, bn1_b, z1, 256);
    head_out_k<<<40,256,0,stream>>>(z1, out_w, out_b, outp);
}

// Round 7
// 1188.590 us; speedup vs baseline: 2.0748x; 1.1135x over previous
//
#include <hip/hip_runtime.h>
#include <hip/hip_bf16.h>

#define BB 16
#define NN 1024
#define KNN 20

// ---------------- fallback: encode ws_size into output if workspace too small ----------------
__global__ void fallback_k(float* __restrict__ out, int n, float c){
    int i = blockIdx.x*256 + threadIdx.x;
    if(i < n) out[i] = c;
}

// ---------------- transpose x [16,1024,3] -> hT [16][3][1024] ----------------
__global__ void transpose3_k(const float* __restrict__ x, float* __restrict__ hT){
    int i = blockIdx.x*256 + threadIdx.x;
    if(i < BB*NN){
        int b = i >> 10, n = i & 1023;
        #pragma unroll
        for(int d=0; d<3; d++)
            hT[((size_t)b*3 + d)*NN + n] = x[(size_t)i*3 + d];
    }
}

// ---------------- transpose hs slice [16,1024,D @stride512] -> hT [16][D][1024] ----------------
template<int D>
__global__ __launch_bounds__(256) void transpose_k(const float* __restrict__ src,  // hs + cbase
                                                   float* __restrict__ hT){
    int nt = blockIdx.x, ct = blockIdx.y, b = blockIdx.z;
    int tid = threadIdx.x;
    __shared__ float tile[64][65];
    int n0 = nt*64, c0 = ct*64;
    for(int l=tid; l<64*64; l+=256){
        int r = l>>6, c = l&63;
        tile[r][c] = src[(size_t)(b*NN + n0 + r)*512 + c0 + c];
    }
    __syncthreads();
    for(int l=tid; l<64*64; l+=256){
        int d = l>>6, n = l&63;
        hT[((size_t)b*D + c0 + d)*NN + n0 + n] = tile[n][d];
    }
}

// ---------------- squared norms from hT (coalesced; fma chain order matches knn3_k) ----------------
template<int D>
__global__ void sqnormT_k(const float* __restrict__ hT, float* __restrict__ sqn){
    int i = blockIdx.x*256 + threadIdx.x;
    if(i < BB*NN){
        int b = i >> 10, n = i & 1023;
        const float* p = hT + (size_t)b*D*NN + n;
        float s = 0.f;
        for(int d=0; d<D; d++){ float v = p[(size_t)d*NN]; s = fmaf(v, v, s); }
        sqn[i] = s;
    }
}

// ---------------- fused dist-GEMM + top-20, all-register (no LDS dist buffer) ----------------
// Block: 16 rows (4 per wave). Lane owns candidates 4*(lane+64*j)+c  (j=0..3, c=0..3)
// -> dist lands directly in the top-k v[16] register layout. B streamed from L2.
// Diagonal exactly 0: same ascending-d fma chain as sqnormT_k; (sa+sq)-2*acc ordering.
template<int D>
__global__ __launch_bounds__(256) void knn3_k(const float* __restrict__ hT,
                                              const float* __restrict__ sqn,
                                              int* __restrict__ idx){
    const int b    = blockIdx.y;
    const int n0   = blockIdx.x * 16;
    const int tid  = threadIdx.x;
    const int lane = tid & 63;
    const int wv   = tid >> 6;

    __shared__ float rowsA[D*16];     // [d][16 rows]
    __shared__ float sqnA[16];

    const float* hTb = hT + (size_t)b*D*NN;
    for(int l=tid; l<16*D; l+=256){
        int d = l >> 4, r = l & 15;
        rowsA[d*16 + r] = hTb[(size_t)d*NN + n0 + r];
    }
    if(tid < 16) sqnA[tid] = sqn[b*NN + n0 + tid];
    __syncthreads();

    const float4* B4 = (const float4*)hTb;
    float4 acc[4][4];                  // [row r][j]
    #pragma unroll
    for(int r=0;r<4;r++)
        #pragma unroll
        for(int j=0;j<4;j++) acc[r][j] = make_float4(0.f,0.f,0.f,0.f);

    #pragma unroll 2
    for(int d=0; d<D; d++){
        float4 a4 = *(const float4*)&rowsA[d*16 + wv*4];
        float4 bv[4];
        #pragma unroll
        for(int j=0;j<4;j++) bv[j] = B4[d*256 + 64*j + lane];
        float ar[4] = {a4.x, a4.y, a4.z, a4.w};
        #pragma unroll
        for(int r=0;r<4;r++)
            #pragma unroll
            for(int j=0;j<4;j++){
                acc[r][j].x = fmaf(ar[r], bv[j].x, acc[r][j].x);
                acc[r][j].y = fmaf(ar[r], bv[j].y, acc[r][j].y);
                acc[r][j].z = fmaf(ar[r], bv[j].z, acc[r][j].z);
                acc[r][j].w = fmaf(ar[r], bv[j].w, acc[r][j].w);
            }
    }

    float4 sq[4];
    #pragma unroll
    for(int j=0;j<4;j++) sq[j] = ((const float4*)(sqn + b*NN))[64*j + lane];

    const float FMAXV = 3.402823466e38f;
    for(int r=0;r<4;r++){
        float sa = sqnA[wv*4 + r];
        float v[16];
        #pragma unroll
        for(int j=0;j<4;j++){
            v[4*j+0] = sa + sq[j].x - 2.f*acc[r][j].x;
            v[4*j+1] = sa + sq[j].y - 2.f*acc[r][j].y;
            v[4*j+2] = sa + sq[j].z - 2.f*acc[r][j].z;
            v[4*j+3] = sa + sq[j].w - 2.f*acc[r][j].w;
        }
        // top-20; ties -> lowest index (matches lax.top_k stability)
        int* out = idx + ((size_t)b*NN + n0 + wv*4 + r)*KNN;
        for(int t=0;t<KNN;t++){
            float bvv = FMAXV; int bi = 0x7fffffff;
            #pragma unroll
            for(int q=0;q<16;q++){
                if(v[q] < bvv){ bvv = v[q]; bi = 4*(lane + 64*(q>>2)) + (q&3); }
            }
            #pragma unroll
            for(int off=32; off>0; off>>=1){
                float ov = __shfl_xor(bvv, off);
                int   oi = __shfl_xor(bi, off);
                if(ov < bvv || (ov == bvv && oi < bi)){ bvv = ov; bi = oi; }
            }
            if(lane == 0) out[t] = bi;
            int ol = (bi >> 2) & 63;
            if(lane == ol){
                int q = ((bi >> 8) << 2) | (bi & 3);
                v[q] = FMAXV;
            }
        }
    }
}

// ---------------- tiled dual GEMM: T = h@theta^T ; U = h@(phi-theta)^T ----------------
template<int D, int O>
__global__ __launch_bounds__(256) void featTU_k(const float* __restrict__ h, int S,
                                                const float* __restrict__ th,
                                                const float* __restrict__ ph,
                                                float* __restrict__ T, float* __restrict__ U){
    int ot = blockIdx.x, nt = blockIdx.y;
    int tid = threadIdx.x, tx = tid & 15, ty = tid >> 4;
    __shared__ float As[64][33];
    __shared__ float Wt[64][33];
    __shared__ float Wp[64][33];
    float acct[4][4] = {};
    float accp[4][4] = {};
    for(int kk=0; kk<D; kk+=32){
        for(int l=tid; l<64*32; l+=256){
            int r = l>>5, c = l&31, d = kk + c;
            As[r][c] = (d < D) ? h[(size_t)(nt*64+r)*S + d] : 0.f;
            Wt[r][c] = (d < D) ? th[(size_t)(ot*64+r)*D + d] : 0.f;
            Wp[r][c] = (d < D) ? ph[(size_t)(ot*64+r)*D + d] : 0.f;
        }
        __syncthreads();
        #pragma unroll
        for(int k=0;k<32;k++){
            float a[4], bt[4], bp[4];
            #pragma unroll
            for(int i=0;i<4;i++) a[i]  = As[ty+16*i][k];
            #pragma unroll
            for(int j=0;j<4;j++){ bt[j] = Wt[tx+16*j][k]; bp[j] = Wp[tx+16*j][k]; }
            #pragma unroll
            for(int i=0;i<4;i++)
                #pragma unroll
                for(int j=0;j<4;j++){
                    acct[i][j] = fmaf(a[i], bt[j], acct[i][j]);
                    accp[i][j] = fmaf(a[i], bp[j], accp[i][j]);
                }
        }
        __syncthreads();
    }
    #pragma unroll
    for(int i=0;i<4;i++){
        int rw = nt*64 + ty + 16*i;
        #pragma unroll
        for(int j=0;j<4;j++){
            int o = ot*64 + tx + 16*j;
            T[(size_t)rw*O + o] = acct[i][j];
            U[(size_t)rw*O + o] = accp[i][j] - acct[i][j];
        }
    }
}

// ---------------- gather 20 neighbors of T, max, + U, leaky ----------------
template<int O>
__global__ __launch_bounds__(256) void gather2_k(const float* __restrict__ T, const float* __restrict__ U,
                                                 const int* __restrict__ idx, float* __restrict__ outp){
    constexpr int P = 256 / O;           // points per block
    int bn0 = blockIdx.x * P;
    int tid = threadIdx.x;
    int p = tid / O, o = tid % O;
    int bn = bn0 + p;
    int b  = bn >> 10;
    __shared__ int nb[P*KNN];
    if(tid < P*KNN){
        int pp = tid / KNN, k = tid % KNN;
        nb[pp*KNN + k] = idx[(size_t)(bn0+pp)*KNN + k] & (NN-1);  // mask: never faults
    }
    __syncthreads();
    const float* Tb = T + (size_t)b*NN*O;
    float m = -3.402823466e38f;
    #pragma unroll
    for(int k=0;k<KNN;k++) m = fmaxf(m, Tb[(size_t)nb[p*KNN+k]*O + o]);
    float v = m + U[(size_t)bn*O + o];
    v = (v > 0.f) ? v : 0.2f*v;
    outp[(size_t)bn*512 + o] = v;
}

// ---------------- projection GEMM: 128x128 tile, 8x8/thread, max-pool epilogue only ----------------
__global__ __launch_bounds__(256) void proj2_k(const float* __restrict__ hs, const float* __restrict__ w,
                                               float* __restrict__ pmax){
    int ot = blockIdx.x;          // 8 col tiles of 128
    int nt = blockIdx.y;          // 8 row tiles of 128 (within batch)
    int b  = blockIdx.z;          // 16
    int tid = threadIdx.x;
    int tx = tid & 15, ty = tid >> 4;
    __shared__ float As[16][132];     // [k][row], padded
    __shared__ float Ws[16][132];     // [k][col]
    __shared__ float red[16][128];
    float acc[8][8] = {};
    const float* ha = hs + ((size_t)b*NN + (size_t)nt*128)*512;
    const float* wa = w + (size_t)ot*128*512;
    for(int kk=0; kk<512; kk+=16){
        __syncthreads();
        #pragma unroll
        for(int q=0; q<2; q++){
            int idx = tid + 256*q;          // 0..511: r=idx>>2 (128 rows), c0=4*(idx&3)
            int r = idx >> 2, c0 = (idx & 3)*4;
            float4 av = *(const float4*)&ha[(size_t)r*512 + kk + c0];
            float4 wv = *(const float4*)&wa[(size_t)r*512 + kk + c0];
            As[c0+0][r] = av.x; As[c0+1][r] = av.y; As[c0+2][r] = av.z; As[c0+3][r] = av.w;
            Ws[c0+0][r] = wv.x; Ws[c0+1][r] = wv.y; Ws[c0+2][r] = wv.z; Ws[c0+3][r] = wv.w;
        }
        __syncthreads();
        #pragma unroll
        for(int k=0;k<16;k++){
            float a[8], bv[8];
            *(float4*)&a[0]  = *(const float4*)&As[k][ty*8];
            *(float4*)&a[4]  = *(const float4*)&As[k][ty*8+4];
            *(float4*)&bv[0] = *(const float4*)&Ws[k][tx*8];
            *(float4*)&bv[4] = *(const float4*)&Ws[k][tx*8+4];
            #pragma unroll
            for(int i=0;i<8;i++)
                #pragma unroll
                for(int j=0;j<8;j++) acc[i][j] = fmaf(a[i], bv[j], acc[i][j]);
        }
    }
    float cmax[8];
    #pragma unroll
    for(int j=0;j<8;j++){
        cmax[j] = acc[0][j];
        #pragma unroll
        for(int i=1;i<8;i++) cmax[j] = fmaxf(cmax[j], acc[i][j]);
    }
    __syncthreads();
    #pragma unroll
    for(int j=0;j<8;j++) red[ty][tx*8+j] = cmax[j];
    __syncthreads();
    if(tid < 128){
        float m = red[0][tid];
        #pragma unroll
        for(int r=1;r<16;r++) m = fmaxf(m, red[r][tid]);
        pmax[((size_t)b*8 + nt)*1024 + ot*128 + tid] = m;
    }
}

// ---------------- column sums of hs: colsum[16][512] (for algebraic mean-pool) ----------------
__global__ void colsum_k(const float* __restrict__ hs, float* __restrict__ colsum){
    int i = blockIdx.x*256 + threadIdx.x;   // b*512 + c
    if(i >= BB*512) return;
    int b = i >> 9, c = i & 511;
    const float* p = hs + (size_t)b*NN*512 + c;
    float s = 0.f;
    for(int n=0;n<NN;n++) s += p[(size_t)n*512];
    colsum[i] = s;
}

// ---------------- combine: max over 8 tiles; mean = colsum@w/1024; + bias ----------------
__global__ __launch_bounds__(256) void pool_final2_k(const float* __restrict__ pmax,
                                                     const float* __restrict__ colsum,
                                                     const float* __restrict__ w,
                                                     const float* __restrict__ pb,
                                                     float* __restrict__ pooled){
    int i = blockIdx.x*256 + threadIdx.x;   // b*1024 + o (block covers one b)
    int b = i >> 10, o = i & 1023;
    __shared__ float cs[512];
    for(int l=threadIdx.x; l<512; l+=256) cs[l] = colsum[b*512 + l];
    __syncthreads();
    float m = -3.402823466e38f;
    #pragma unroll
    for(int t=0;t<8;t++) m = fmaxf(m, pmax[((size_t)b*8 + t)*1024 + o]);
    float s = 0.f;
    const float4* w4 = (const float4*)(w + (size_t)o*512);
    const float4* c4 = (const float4*)cs;
    for(int d=0; d<128; d++){
        float4 wv = w4[d]; float4 cv = c4[d];
        s = fmaf(cv.x, wv.x, s); s = fmaf(cv.y, wv.y, s);
        s = fmaf(cv.z, wv.z, s); s = fmaf(cv.w, wv.w, s);
    }
    float bias = pb[o];
    pooled[b*2048 + o]        = m + bias;
    pooled[b*2048 + 1024 + o] = s * (1.f/1024.f) + bias;
}

// ---------------- head FC + BatchNorm(batch of 16) + leaky; one block per feature ----------------
template<int IN>
__global__ __launch_bounds__(256) void head_bn_k(const float* __restrict__ in, const float* __restrict__ w,
                                                 const float* __restrict__ bias, const float* __restrict__ g,
                                                 const float* __restrict__ bt, float* __restrict__ out, int OUT){
    int o = blockIdx.x;
    int tid = threadIdx.x, bb = tid >> 4, s = tid & 15;
    const float* ir = in + (size_t)bb*IN;
    const float* wr = w  + (size_t)o*IN;
    float acc = 0.f;
    for(int d=s; d<IN; d+=16) acc = fmaf(ir[d], wr[d], acc);
    #pragma unroll
    for(int off=8; off>0; off>>=1) acc += __shfl_xor(acc, off);
    __shared__ float vals[16];
    __shared__ float stats[2];
    if(s == 0) vals[bb] = acc + bias[o];
    __syncthreads();
    if(tid == 0){
        float mu = 0.f;
        for(int q=0;q<16;q++) mu += vals[q];
        mu *= (1.f/16.f);
        float var = 0.f;
        for(int q=0;q<16;q++){ float d = vals[q]-mu; var = fmaf(d,d,var); }
        var *= (1.f/16.f);
        stats[0] = mu; stats[1] = rsqrtf(var + 1e-5f);
    }
    __syncthreads();
    if(s == 0){
        float v = (vals[bb]-stats[0])*stats[1]*g[o] + bt[o];
        v = (v > 0.f) ? v : 0.2f*v;
        out[(size_t)bb*OUT + o] = v;
    }
}

// ---------------- final linear -> f32 out [16,40] ----------------
__global__ __launch_bounds__(256) void head_out_k(const float* __restrict__ in, const float* __restrict__ w,
                                                  const float* __restrict__ bias, float* __restrict__ out){
    int o = blockIdx.x;   // 40
    int tid = threadIdx.x, bb = tid >> 4, s = tid & 15;
    const float* ir = in + (size_t)bb*256;
    float acc = 0.f;
    for(int d=s; d<256; d+=16) acc = fmaf(ir[d], w[o*256+d], acc);
    #pragma unroll
    for(int off=8; off>0; off>>=1) acc += __shfl_xor(acc, off);
    if(s == 0) out[bb*40 + o] = acc + bias[o];
}

extern "C" void kernel_launch(void* const* d_in, const int* in_sizes, int n_in,
                              void* d_out, int out_size, void* d_ws, size_t ws_size,
                              hipStream_t stream) {
    const float* x       = (const float*)d_in[0];
    const float* th[4]   = {(const float*)d_in[1], (const float*)d_in[3], (const float*)d_in[5], (const float*)d_in[7]};
    const float* ph[4]   = {(const float*)d_in[2], (const float*)d_in[4], (const float*)d_in[6], (const float*)d_in[8]};
    const float* proj_w  = (const float*)d_in[9];
    const float* proj_b  = (const float*)d_in[10];
    const float* emb0_w  = (const float*)d_in[11];
    const float* emb0_b  = (const float*)d_in[12];
    const float* bn0_g   = (const float*)d_in[13];
    const float* bn0_b   = (const float*)d_in[14];
    const float* emb1_w  = (const float*)d_in[15];
    const float* emb1_b  = (const float*)d_in[16];
    const float* bn1_g   = (const float*)d_in[17];
    const float* bn1_b   = (const float*)d_in[18];
    const float* out_w   = (const float*)d_in[19];
    const float* out_b   = (const float*)d_in[20];
    float* outp = (float*)d_out;

    // workspace layout (float elements) — unchanged (guard passed at 68.5 MB)
    const size_t OFF_HS  = 0;                       // 16384 x 512 = 8,388,608
    const size_t OFF_T   = 8388608;                 // 16384 x 256 = 4,194,304
    const size_t OFF_U   = 12582912;                // 16384 x 256 = 4,194,304
    const size_t OFF_SQN = 16777216;                // 16384
    const size_t OFF_IDX = 16793600;                // 16384 x 20 ints = 327,680
    const size_t REQ_FL  = 17121280;
    const size_t REQ     = REQ_FL * 4;              // 68,485,120 bytes

    if(ws_size < REQ){
        fallback_k<<<(out_size+255)/256, 256, 0, stream>>>(outp, out_size, (float)((double)ws_size*1e-6));
        return;
    }

    float* Wf   = (float*)d_ws;
    float* hs   = Wf + OFF_HS;
    float* T    = Wf + OFF_T;
    float* U    = Wf + OFF_U;
    float* sqn  = Wf + OFF_SQN;
    int*   idxb = (int*)(Wf + OFF_IDX);
    // hT aliases T region (max 16x128x1024 = 8 MB <= 16 MB); hT dead before featTU writes T
    float* hT   = T;
    // post-layer aliases inside T region (dead after last gather)
    float* pmax   = T;                 // 16*8*1024 = 131072
    float* colsum = T + 131072;        // 16*512   = 8192
    float* pooled = T + 147456;        // 16*2048  = 32768
    float* z0     = T + 180224;        // 16*512
    float* z1     = T + 188416;        // 16*256

    // ---- layer 0: h=x (S=3,D=3) -> O=64 at hs ch 0
    transpose3_k<<<64,256,0,stream>>>(x, hT);
    sqnormT_k<3><<<64,256,0,stream>>>(hT, sqn);
    knn3_k<3><<<dim3(64,16),256,0,stream>>>(hT, sqn, idxb);
    featTU_k<3,64><<<dim3(1,256),256,0,stream>>>(x, 3, th[0], ph[0], T, U);
    gather2_k<64><<<BB*NN/4,256,0,stream>>>(T, U, idxb, hs + 0);

    // ---- layer 1: h=hs[:,0:64] (S=512,D=64) -> O=64 at ch 64
    transpose_k<64><<<dim3(16,1,16),256,0,stream>>>(hs + 0, hT);
    sqnormT_k<64><<<64,256,0,stream>>>(hT, sqn);
    knn3_k<64><<<dim3(64,16),256,0,stream>>>(hT, sqn, idxb);
    featTU_k<64,64><<<dim3(1,256),256,0,stream>>>(hs + 0, 512, th[1], ph[1], T, U);
    gather2_k<64><<<BB*NN/4,256,0,stream>>>(T, U, idxb, hs + 64);

    // ---- layer 2: h=hs[:,64:128] (D=64) -> O=128 at ch 128
    transpose_k<64><<<dim3(16,1,16),256,0,stream>>>(hs + 64, hT);
    sqnormT_k<64><<<64,256,0,stream>>>(hT, sqn);
    knn3_k<64><<<dim3(64,16),256,0,stream>>>(hT, sqn, idxb);
    featTU_k<64,128><<<dim3(2,256),256,0,stream>>>(hs + 64, 512, th[2], ph[2], T, U);
    gather2_k<128><<<BB*NN/2,256,0,stream>>>(T, U, idxb, hs + 128);

    // ---- layer 3: h=hs[:,128:256] (D=128) -> O=256 at ch 256
    transpose_k<128><<<dim3(16,2,16),256,0,stream>>>(hs + 128, hT);
    sqnormT_k<128><<<64,256,0,stream>>>(hT, sqn);
    knn3_k<128><<<dim3(64,16),256,0,stream>>>(hT, sqn, idxb);
    featTU_k<128,256><<<dim3(4,256),256,0,stream>>>(hs + 128, 512, th[3], ph[3], T, U);
    gather2_k<256><<<BB*NN,256,0,stream>>>(T, U, idxb, hs + 256);

    // ---- projection + pooling (max via tiled GEMM; mean via colsum @ w)
    proj2_k<<<dim3(8,8,16),256,0,stream>>>(hs, proj_w, pmax);
    colsum_k<<<32,256,0,stream>>>(hs, colsum);
    pool_final2_k<<<64,256,0,stream>>>(pmax, colsum, proj_w, proj_b, pooled);

    // ---- head
    head_bn_k<2048><<<512,256,0,stream>>>(pooled, emb0_w, emb0_b, bn0_g, bn0_b, z0, 512);
    head_bn_k<512><<<256,256,0,stream>>>(z0, emb1_w, emb1_b, bn1_g, bn1_b, z1, 256);
    head_out_k<<<40,256,0,stream>>>(z1, out_w, out_b, outp);
}